// Round 6
// baseline (702.506 us; speedup 1.0000x reference)
//
#include <hip/hip_runtime.h>
#include <math.h>

#define BB 8
#define LL 8192
#define DD 64
#define HH 128
#define NN 64
#define NLAYER 3

// workspace sizes in floats
#define SZ_H   ((size_t)BB*LL*HH)            // 8388608
#define SZ_P   ((size_t)HH*NN*2)             // 16384
#define SZ_WG4 ((size_t)NLAYER*HH*64*4)      // 98304  (paired-col float4 layout)
#define SZ_WO4 ((size_t)32*64*4)             // 8192
#define SZ_WI4 ((size_t)16*128*4)            // 8192

// ---------------- packed fp32 helpers (v_pk_fma_f32 = 2 FMA/lane/instr) ----------------
__device__ __forceinline__ float2 pk_fma(float2 a, float2 b, float2 c) {
  float2 d;
  asm("v_pk_fma_f32 %0, %1, %2, %3" : "=v"(d) : "v"(a), "v"(b), "v"(c));
  return d;
}
// src1 component-swapped: lo result uses b.y, hi result uses b.x
__device__ __forceinline__ float2 pk_fma_sw1(float2 a, float2 b, float2 c) {
  float2 d;
  asm("v_pk_fma_f32 %0, %1, %2, %3 op_sel:[0,1,0] op_sel_hi:[1,0,1]"
      : "=v"(d) : "v"(a), "v"(b), "v"(c));
  return d;
}

// ---------------- weight repack kernels ----------------
__global__ __launch_bounds__(256) void kW1(const float* __restrict__ Wglu,
                                           float4* __restrict__ wpk4) {
  int tid = blockIdx.x*256 + threadIdx.x;        // < 3*128*64 = 24576
  int l   = tid >> 13;
  int rem = tid & 8191;
  int h   = rem >> 6;
  int ct  = rem & 63;
  const float* base = Wglu + (size_t)l*256*128 + h;
  wpk4[tid] = make_float4(base[(2*ct)*128], base[(2*ct+1)*128],
                          base[(2*ct+128)*128], base[(2*ct+129)*128]);
}

__global__ __launch_bounds__(256) void kW2(const float* __restrict__ Wout,
                                           float4* __restrict__ wo4) {
  int tid = blockIdx.x*256 + threadIdx.x;        // < 2048
  int h4 = tid >> 6, d = tid & 63;
  wo4[tid] = make_float4(Wout[(4*h4+0)*DD + d], Wout[(4*h4+1)*DD + d],
                         Wout[(4*h4+2)*DD + d], Wout[(4*h4+3)*DD + d]);
}

__global__ __launch_bounds__(256) void kW3(const float* __restrict__ Win,
                                           float4* __restrict__ wip4) {
  int tid = blockIdx.x*256 + threadIdx.x;        // < 2048
  int k4 = tid >> 7, col = tid & 127;
  wip4[tid] = make_float4(Win[(4*k4+0)*HH + col], Win[(4*k4+1)*HH + col],
                          Win[(4*k4+2)*HH + col], Win[(4*k4+3)*HH + col]);
}

// ---------------- input GEMM: h = x @ W_in + b_in ----------------
__global__ __launch_bounds__(256) void kIn(const float* __restrict__ x,
      const float4* __restrict__ wip4, const float* __restrict__ bin,
      float* __restrict__ hout) {
  __shared__ float xs[32][DD];
  size_t row0 = (size_t)blockIdx.x * 32;
  int t = threadIdx.x;
  #pragma unroll
  for (int k = 0; k < 2; k++) {
    int idx = t + k*256;
    int r = idx >> 4, c4 = idx & 15;
    *reinterpret_cast<float4*>(&xs[r][c4*4]) =
        *reinterpret_cast<const float4*>(&x[(row0 + r)*DD + c4*4]);
  }
  __syncthreads();
  int ct = t & 63, rg = t >> 6;
  float acc[8][2];
  float b0 = bin[2*ct], b1 = bin[2*ct+1];
  #pragma unroll
  for (int r = 0; r < 8; r++) { acc[r][0] = b0; acc[r][1] = b1; }
  for (int k4 = 0; k4 < 16; k4++) {
    float4 w0 = wip4[k4*128 + 2*ct];
    float4 w1 = wip4[k4*128 + 2*ct+1];
    #pragma unroll
    for (int r = 0; r < 8; r++) {
      const float4 x4 = *reinterpret_cast<const float4*>(&xs[rg*8 + r][k4*4]);
      acc[r][0] = fmaf(x4.x, w0.x, fmaf(x4.y, w0.y, fmaf(x4.z, w0.z, fmaf(x4.w, w0.w, acc[r][0]))));
      acc[r][1] = fmaf(x4.x, w1.x, fmaf(x4.y, w1.y, fmaf(x4.z, w1.z, fmaf(x4.w, w1.w, acc[r][1]))));
    }
  }
  #pragma unroll
  for (int r = 0; r < 8; r++) {
    float2 v = make_float2(acc[r][0], acc[r][1]);
    *reinterpret_cast<float2*>(&hout[(row0 + rg*8 + r)*HH + 2*ct]) = v;
  }
}

// ---------------- per-layer SSM parameter precompute ----------------
// nsq = log2(LCHUNK): squarings to form w^LCHUNK
__global__ __launch_bounds__(256) void kP(const float* __restrict__ logdt,
   const float* __restrict__ logA, const float* __restrict__ Aim,
   const float* __restrict__ Cre, const float* __restrict__ Cim, int layer, int nsq,
   float* __restrict__ wb, float* __restrict__ cb, float* __restrict__ wl) {
  int tid = blockIdx.x*256 + threadIdx.x;        // < HH*NN = 8192
  int n = tid & 63, h = tid >> 6;
  float dt = expf(logdt[layer*HH + h]);
  int idx = (layer*HH + h)*NN + n;
  float ar = -expf(logA[idx]);
  float ai = Aim[idx];
  float dr = dt*ar, di = dt*ai;
  float er = expf(dr);
  float wr_ = er*cosf(di), wi_ = er*sinf(di);     // w = exp(dt*A)
  float mr = wr_ - 1.f, mi = wi_;                 // expm1(dtA)
  float inv = 1.f/(ar*ar + ai*ai);
  float tr = (mr*ar + mi*ai)*inv;                 // expm1(dtA)/A
  float ti = (mi*ar - mr*ai)*inv;
  float c0 = Cre[idx], c1 = Cim[idx];
  cb[2*tid]   = c0*tr - c1*ti;                    // C_eff
  cb[2*tid+1] = c0*ti + c1*tr;
  wb[2*tid]   = wr_;
  wb[2*tid+1] = wi_;
  float pr = wr_, pi = wi_;                       // w^LCHUNK via nsq squarings
  for (int k = 0; k < nsq; k++) { float qr = pr*pr - pi*pi; float qi = 2.f*pr*pi; pr = qr; pi = qi; }
  wl[2*tid] = pr; wl[2*tid+1] = pi;
}

// ---------------- kA: chunk-local end states (zero init), packed math ----------------
// wave: lane = g*8+j, h = hg*8+g, lane owns states n = j*8..j*8+7
template<int LOG2NC>
__global__ __launch_bounds__(256) void kA(const float* __restrict__ hin,
        const float* __restrict__ wbuf, float* __restrict__ Sloc) {
  constexpr int NC = 1 << LOG2NC;
  constexpr int LC = LL >> LOG2NC;
  int wid  = blockIdx.x*4 + (threadIdx.x >> 6);
  int lane = threadIdx.x & 63;
  int c  = wid & (NC-1);
  int hg = (wid >> LOG2NC) & 15;
  int b  = wid >> (LOG2NC + 4);
  int g = lane >> 3, j = lane & 7;
  int h = hg*8 + g;
  int n0 = j*8;
  float2 W1[8], W2[8], S[8];
  const float* wp = wbuf + ((size_t)h*NN + n0)*2;
  #pragma unroll
  for (int q = 0; q < 8; q++) {
    float wr = wp[2*q], wi = wp[2*q+1];
    W1[q] = make_float2(wr, wr);
    W2[q] = make_float2(-wi, wi);
    S[q]  = make_float2(0.f, 0.f);
  }
  const float* up = hin + (size_t)b*LL*HH + h;
  int l0 = c*LC;
  for (int lb = 0; lb < LC; lb += 8) {
    float uv[8];
    #pragma unroll
    for (int q = 0; q < 8; q++) uv[q] = up[(size_t)(l0 + lb + q)*HH];
    #pragma unroll
    for (int q = 0; q < 8; q++) {
      float2 U = make_float2(uv[q], 0.f);
      #pragma unroll
      for (int st = 0; st < 8; st++) {
        float2 T = pk_fma(W1[st], S[st], U);
        S[st] = pk_fma_sw1(W2[st], S[st], T);
      }
    }
  }
  float2* Sp = (float2*)(Sloc + ((((size_t)b*HH + h)*NC + c)*NN + n0)*2);
  #pragma unroll
  for (int q = 0; q < 8; q++) Sp[q] = S[q];
}

// ---------------- kB: cross-chunk scan ----------------
template<int LOG2NC>
__global__ __launch_bounds__(256) void kB(float* __restrict__ Sloc,
                                          const float* __restrict__ wl) {
  constexpr int NC = 1 << LOG2NC;
  int tid = blockIdx.x*256 + threadIdx.x;        // < BB*HH*NN = 65536
  int n = tid & 63;
  int h = (tid >> 6) & 127;
  int b = tid >> 13;
  float wlr = wl[((size_t)h*NN + n)*2], wli = wl[((size_t)h*NN + n)*2 + 1];
  float cr = 0.f, ci = 0.f;
  float* base = Sloc + (((size_t)b*HH + h)*NC)*NN*2 + (size_t)n*2;
  for (int c = 0; c < NC; c++) {
    float* p = base + (size_t)c*NN*2;
    float tr_ = p[0], ti_ = p[1];
    p[0] = cr; p[1] = ci;
    float nr = fmaf(wlr, cr, fmaf(-wli, ci, tr_));
    float ni = fmaf(wli, cr, fmaf(wlr, ci, ti_));
    cr = nr; ci = ni;
  }
}

// ---------------- kC: full recurrence from s_init, packed math ----------------
template<int LOG2NC>
__global__ __launch_bounds__(256) void kC(const float* __restrict__ hin,
        const float* __restrict__ wbuf, const float* __restrict__ cbuf,
        const float* __restrict__ Sini, float* __restrict__ y) {
  constexpr int NC = 1 << LOG2NC;
  constexpr int LC = LL >> LOG2NC;
  int wid  = blockIdx.x*4 + (threadIdx.x >> 6);
  int lane = threadIdx.x & 63;
  int c  = wid & (NC-1);
  int hg = (wid >> LOG2NC) & 15;
  int b  = wid >> (LOG2NC + 4);
  int g = lane >> 3, j = lane & 7;
  int h = hg*8 + g;
  int n0 = j*8;
  float2 W1[8], W2[8], C2[8], S[8];
  {
    const float* wp = wbuf + ((size_t)h*NN + n0)*2;
    const float* cp = cbuf + ((size_t)h*NN + n0)*2;
    const float2* sp = (const float2*)(Sini + ((((size_t)b*HH + h)*NC + c)*NN + n0)*2);
    #pragma unroll
    for (int q = 0; q < 8; q++) {
      float wr = wp[2*q], wi = wp[2*q+1];
      W1[q] = make_float2(wr, wr);
      W2[q] = make_float2(-wi, wi);
      C2[q] = make_float2(cp[2*q], -cp[2*q+1]);
      S[q]  = sp[q];
    }
  }
  const float* up = hin + (size_t)b*LL*HH + h;
  float* yp = y + (size_t)b*LL*HH;
  int l0 = c*LC;
  for (int lb = 0; lb < LC; lb += 8) {
    float uv[8];
    #pragma unroll
    for (int q = 0; q < 8; q++) uv[q] = up[(size_t)(l0 + lb + q)*HH];
    float ystore = 0.f;
    #pragma unroll
    for (int q = 0; q < 8; q++) {
      float2 U = make_float2(uv[q], 0.f);
      float2 Y = make_float2(0.f, 0.f);
      #pragma unroll
      for (int st = 0; st < 8; st++) {
        float2 T = pk_fma(W1[st], S[st], U);
        S[st] = pk_fma_sw1(W2[st], S[st], T);
        Y = pk_fma(C2[st], S[st], Y);
      }
      float yv = Y.x + Y.y;                       // Re(C~ . s) partial (8 states)
      yv += __shfl_xor(yv, 1);
      yv += __shfl_xor(yv, 2);
      yv += __shfl_xor(yv, 4);
      if (j == q) ystore = 2.f*yv;
    }
    yp[(size_t)(l0 + lb + j)*HH + h] = ystore;
  }
}

// ---------------- kD: skip + gelu + GLU + residual + rmsnorm ----------------
// block: 32 rows. thread: ct=t&63 -> cols {2ct,2ct+1,2ct+128,2ct+129}; rg=t>>6 -> 8 rows.
// acc[8][4]=32 VGPRs, no min-occupancy hint (r3 lesson: acc[16][4]+bounds(,4) spilled).
// y may alias hout.
__global__ __launch_bounds__(256) void kD(const float* __restrict__ y,
     const float* __restrict__ hin, const float* __restrict__ dskip,
     const float4* __restrict__ wpk4, const float* __restrict__ bglu,
     float* __restrict__ hout) {
  __shared__ float yy[32][HH];      // 16 KB
  __shared__ float rnorm[32];
  size_t row0 = (size_t)blockIdx.x * 32;
  int t = threadIdx.x;
  #pragma unroll
  for (int k = 0; k < 4; k++) {
    int idx = t + k*256;
    int r = idx >> 5, c4 = idx & 31;
    const float4 u4 = *reinterpret_cast<const float4*>(&hin[(row0 + r)*HH + c4*4]);
    const float4 y4 = *reinterpret_cast<const float4*>(&y[(row0 + r)*HH + c4*4]);
    const float4 d4 = *reinterpret_cast<const float4*>(&dskip[c4*4]);
    float v[4] = { fmaf(u4.x, d4.x, y4.x), fmaf(u4.y, d4.y, y4.y),
                   fmaf(u4.z, d4.z, y4.z), fmaf(u4.w, d4.w, y4.w) };
    float o[4];
    #pragma unroll
    for (int q = 0; q < 4; q++) {
      float vv = v[q];
      float arg = 0.7978845608028654f*(vv + 0.044715f*vv*vv*vv);
      arg = fminf(fmaxf(arg, -15.f), 15.f);
      float e = __expf(2.f*arg);
      float th = (e - 1.f)/(e + 1.f);
      o[q] = 0.5f*vv*(1.f + th);
    }
    *reinterpret_cast<float4*>(&yy[r][c4*4]) = make_float4(o[0], o[1], o[2], o[3]);
  }
  __syncthreads();
  int ct = t & 63, rg = t >> 6;
  float acc[8][4];
  {
    float b0 = bglu[2*ct], b1 = bglu[2*ct+1], b2 = bglu[2*ct+128], b3 = bglu[2*ct+129];
    #pragma unroll
    for (int r = 0; r < 8; r++) { acc[r][0] = b0; acc[r][1] = b1; acc[r][2] = b2; acc[r][3] = b3; }
  }
  for (int h4 = 0; h4 < 32; h4++) {
    float4 w0 = wpk4[(h4*4+0)*64 + ct];
    float4 w1 = wpk4[(h4*4+1)*64 + ct];
    float4 w2 = wpk4[(h4*4+2)*64 + ct];
    float4 w3 = wpk4[(h4*4+3)*64 + ct];
    #pragma unroll
    for (int r = 0; r < 8; r++) {
      const float4 y4 = *reinterpret_cast<const float4*>(&yy[rg*8 + r][h4*4]);
      acc[r][0] = fmaf(y4.x, w0.x, fmaf(y4.y, w1.x, fmaf(y4.z, w2.x, fmaf(y4.w, w3.x, acc[r][0]))));
      acc[r][1] = fmaf(y4.x, w0.y, fmaf(y4.y, w1.y, fmaf(y4.z, w2.y, fmaf(y4.w, w3.y, acc[r][1]))));
      acc[r][2] = fmaf(y4.x, w0.z, fmaf(y4.y, w1.z, fmaf(y4.z, w2.z, fmaf(y4.w, w3.z, acc[r][2]))));
      acc[r][3] = fmaf(y4.x, w0.w, fmaf(y4.y, w1.w, fmaf(y4.z, w2.w, fmaf(y4.w, w3.w, acc[r][3]))));
    }
  }
  __syncthreads();
  #pragma unroll
  for (int r = 0; r < 8; r++) {
    size_t grow = row0 + rg*8 + r;
    const float2 res = *reinterpret_cast<const float2*>(&hin[grow*HH + 2*ct]);
    float s0 = 1.f/(1.f + __expf(-acc[r][2]));
    float s1 = 1.f/(1.f + __expf(-acc[r][3]));
    float2 v = make_float2(fmaf(acc[r][0], s0, res.x), fmaf(acc[r][1], s1, res.y));
    *reinterpret_cast<float2*>(&yy[rg*8 + r][2*ct]) = v;
  }
  __syncthreads();
  {
    const float* flat = &yy[0][0];
    #pragma unroll
    for (int i = 0; i < 4; i++) {
      int idx = i*256 + t;
      int row = idx >> 5;
      const float4 f = *reinterpret_cast<const float4*>(&flat[idx*4]);
      float s = fmaf(f.x, f.x, fmaf(f.y, f.y, fmaf(f.z, f.z, f.w*f.w)));
      s += __shfl_xor(s, 1); s += __shfl_xor(s, 2); s += __shfl_xor(s, 4);
      s += __shfl_xor(s, 8); s += __shfl_xor(s, 16);
      if ((t & 31) == 0) rnorm[row] = s;
    }
  }
  __syncthreads();
  #pragma unroll
  for (int k = 0; k < 4; k++) {
    int idx = t + k*256;
    int r = idx >> 5, c4 = idx & 31;
    float scale = 11.313708498984761f / fmaxf(sqrtf(rnorm[r]), 1e-12f);
    float4 f = *reinterpret_cast<const float4*>(&yy[r][c4*4]);
    f.x *= scale; f.y *= scale; f.z *= scale; f.w *= scale;
    *reinterpret_cast<float4*>(&hout[(row0 + r)*HH + c4*4]) = f;
  }
}

// ---------------- kE: out = h @ W_out + b_out ----------------
__global__ __launch_bounds__(256) void kE(const float* __restrict__ hin,
      const float4* __restrict__ wo4, const float* __restrict__ bout,
      float* __restrict__ out) {
  __shared__ float hs[64][HH];
  size_t row0 = (size_t)blockIdx.x * 64;
  int t = threadIdx.x;
  #pragma unroll
  for (int k = 0; k < 8; k++) {
    int idx = t + k*256;
    int r = idx >> 5, c4 = idx & 31;
    *reinterpret_cast<float4*>(&hs[r][c4*4]) =
        *reinterpret_cast<const float4*>(&hin[(row0 + r)*HH + c4*4]);
  }
  __syncthreads();
  int ct = t & 31, rg = t >> 5;
  float acc[8][2];
  float b0 = bout[2*ct], b1 = bout[2*ct+1];
  #pragma unroll
  for (int r = 0; r < 8; r++) { acc[r][0] = b0; acc[r][1] = b1; }
  for (int h4 = 0; h4 < 32; h4++) {
    float4 w0 = wo4[h4*64 + 2*ct];
    float4 w1 = wo4[h4*64 + 2*ct+1];
    #pragma unroll
    for (int r = 0; r < 8; r++) {
      const float4 h4v = *reinterpret_cast<const float4*>(&hs[rg*8 + r][h4*4]);
      acc[r][0] = fmaf(h4v.x, w0.x, fmaf(h4v.y, w0.y, fmaf(h4v.z, w0.z, fmaf(h4v.w, w0.w, acc[r][0]))));
      acc[r][1] = fmaf(h4v.x, w1.x, fmaf(h4v.y, w1.y, fmaf(h4v.z, w1.z, fmaf(h4v.w, w1.w, acc[r][1]))));
    }
  }
  #pragma unroll
  for (int r = 0; r < 8; r++) {
    float2 v = make_float2(acc[r][0], acc[r][1]);
    *reinterpret_cast<float2*>(&out[(row0 + rg*8 + r)*DD + 2*ct]) = v;
  }
}

extern "C" void kernel_launch(void* const* d_in, const int* in_sizes, int n_in,
                              void* d_out, int out_size, void* d_ws, size_t ws_size,
                              hipStream_t stream) {
  const float* x     = (const float*)d_in[0];
  const float* Win   = (const float*)d_in[1];
  const float* bin   = (const float*)d_in[2];
  const float* logdt = (const float*)d_in[3];
  const float* logA  = (const float*)d_in[4];
  const float* Aim   = (const float*)d_in[5];
  const float* Cre   = (const float*)d_in[6];
  const float* Cim   = (const float*)d_in[7];
  const float* Dsk   = (const float*)d_in[8];
  const float* Wglu  = (const float*)d_in[9];
  const float* bglu  = (const float*)d_in[10];
  const float* Wout  = (const float*)d_in[11];
  const float* bout  = (const float*)d_in[12];
  float* out = (float*)d_out;

  // layout: small buffers first so Sl (variable size) goes last
  float* ws  = (float*)d_ws;
  float* wb  = ws;
  float* cb  = wb + SZ_P;
  float* wl  = cb + SZ_P;
  float* wg4 = wl + SZ_P;
  float* wo4 = wg4 + SZ_WG4;
  float* wi4 = wo4 + SZ_WO4;
  float* hA  = wi4 + SZ_WI4;
  float* hB  = hA + SZ_H;
  float* Sl  = hB + SZ_H;

  size_t base_floats = 3*SZ_P + SZ_WG4 + SZ_WO4 + SZ_WI4 + 2*SZ_H;
  bool use64 = ws_size >= (base_floats + (size_t)BB*HH*64*NN*2) * sizeof(float);

  kW1<<<dim3(96), dim3(256), 0, stream>>>(Wglu, (float4*)wg4);
  kW2<<<dim3(8),  dim3(256), 0, stream>>>(Wout, (float4*)wo4);
  kW3<<<dim3(8),  dim3(256), 0, stream>>>(Win,  (float4*)wi4);
  kIn<<<dim3(2048), dim3(256), 0, stream>>>(x, (const float4*)wi4, bin, hA);

  float* hc = hA;
  float* hn = hB;
  for (int layer = 0; layer < NLAYER; ++layer) {
    if (use64) {
      kP<<<dim3(32), dim3(256), 0, stream>>>(logdt, logA, Aim, Cre, Cim, layer, 7, wb, cb, wl);
      kA<6><<<dim3(2048), dim3(256), 0, stream>>>(hc, wb, Sl);
      kB<6><<<dim3(256),  dim3(256), 0, stream>>>(Sl, wl);
      kC<6><<<dim3(2048), dim3(256), 0, stream>>>(hc, wb, cb, Sl, hn);
    } else {
      kP<<<dim3(32), dim3(256), 0, stream>>>(logdt, logA, Aim, Cre, Cim, layer, 8, wb, cb, wl);
      kA<5><<<dim3(1024), dim3(256), 0, stream>>>(hc, wb, Sl);
      kB<5><<<dim3(256),  dim3(256), 0, stream>>>(Sl, wl);
      kC<5><<<dim3(1024), dim3(256), 0, stream>>>(hc, wb, cb, Sl, hn);
    }
    kD<<<dim3(2048), dim3(256), 0, stream>>>(hn, hc, Dsk + layer*HH,
                       (const float4*)(wg4 + (size_t)layer*HH*64*4),
                       bglu + layer*2*HH, hn);
    float* tmp = hc; hc = hn; hn = tmp;
  }
  kE<<<dim3(1024), dim3(256), 0, stream>>>(hc, (const float4*)wo4, bout, out);
}

// Round 7
// 554.773 us; speedup vs baseline: 1.2663x; 1.2663x over previous
//
#include <hip/hip_runtime.h>
#include <math.h>

#define BB 8
#define LL 8192
#define DD 64
#define HH 128
#define NN 64
#define NLAYER 3
#define LC 64          // chunk length
#define NC 128         // chunks per (b,h) sequence

typedef _Float16 half_t;
typedef _Float16 f16x8_t __attribute__((ext_vector_type(8)));
typedef _Float16 f16x4_t __attribute__((ext_vector_type(4)));
typedef float    f32x4_t __attribute__((ext_vector_type(4)));

// workspace sizes in float units
#define SZ_WB   ((size_t)HH*NN*2)            // 16384 (w complex fp32)
#define SZ_WL   ((size_t)HH*NN*2)            // 16384 (w^64 complex fp32)
#define SZ_WG4  ((size_t)NLAYER*HH*64*4)     // 98304
#define SZ_WO4  ((size_t)32*64*4)            // 8192
#define SZ_WI4  ((size_t)16*128*4)           // 8192
#define SZ_AM   ((size_t)HH*64*192/2)        // 786432  (f16 [h][64 l][192 k])
#define SZ_SB   ((size_t)HH*BB*NC*128/2)     // 8388608 (f16 [h][b][c][128 n2])
#define SZ_HT   ((size_t)BB*HH*LL/2)         // 4194304 (f16 [b][h][l])
#define SZ_YT   ((size_t)BB*HH*LL/2)         // 4194304 (f16 [b][h][l])
#define SZ_H    ((size_t)BB*LL*HH)           // 8388608 (fp32 residual stream)

// ---------------- weight repack kernels (unchanged) ----------------
__global__ __launch_bounds__(256) void kW1(const float* __restrict__ Wglu,
                                           float4* __restrict__ wpk4) {
  int tid = blockIdx.x*256 + threadIdx.x;        // < 3*128*64
  int l   = tid >> 13;
  int rem = tid & 8191;
  int h   = rem >> 6;
  int ct  = rem & 63;
  const float* base = Wglu + (size_t)l*256*128 + h;
  wpk4[tid] = make_float4(base[(2*ct)*128], base[(2*ct+1)*128],
                          base[(2*ct+128)*128], base[(2*ct+129)*128]);
}
__global__ __launch_bounds__(256) void kW2(const float* __restrict__ Wout,
                                           float4* __restrict__ wo4) {
  int tid = blockIdx.x*256 + threadIdx.x;        // < 2048
  int h4 = tid >> 6, d = tid & 63;
  wo4[tid] = make_float4(Wout[(4*h4+0)*DD + d], Wout[(4*h4+1)*DD + d],
                         Wout[(4*h4+2)*DD + d], Wout[(4*h4+3)*DD + d]);
}
__global__ __launch_bounds__(256) void kW3(const float* __restrict__ Win,
                                           float4* __restrict__ wip4) {
  int tid = blockIdx.x*256 + threadIdx.x;        // < 2048
  int k4 = tid >> 7, col = tid & 127;
  wip4[tid] = make_float4(Win[(4*k4+0)*HH + col], Win[(4*k4+1)*HH + col],
                          Win[(4*k4+2)*HH + col], Win[(4*k4+3)*HH + col]);
}

// ---------------- kIn: h = x @ W_in + b_in ; dual-write fp32 (b,l,h) + f16 [b][h][l] ----------------
__global__ __launch_bounds__(256) void kIn(const float* __restrict__ x,
      const float4* __restrict__ wip4, const float* __restrict__ bin,
      float* __restrict__ hout, half_t* __restrict__ hT) {
  __shared__ float xs[32][DD];
  size_t row0 = (size_t)blockIdx.x * 32;
  int t = threadIdx.x;
  #pragma unroll
  for (int k = 0; k < 2; k++) {
    int idx = t + k*256;
    int r = idx >> 4, c4 = idx & 15;
    *reinterpret_cast<float4*>(&xs[r][c4*4]) =
        *reinterpret_cast<const float4*>(&x[(row0 + r)*DD + c4*4]);
  }
  __syncthreads();
  int ct = t & 63, rg = t >> 6;
  float acc[8][2];
  float b0 = bin[2*ct], b1 = bin[2*ct+1];
  #pragma unroll
  for (int r = 0; r < 8; r++) { acc[r][0] = b0; acc[r][1] = b1; }
  for (int k4 = 0; k4 < 16; k4++) {
    float4 w0 = wip4[k4*128 + 2*ct];
    float4 w1 = wip4[k4*128 + 2*ct+1];
    #pragma unroll
    for (int r = 0; r < 8; r++) {
      const float4 x4 = *reinterpret_cast<const float4*>(&xs[rg*8 + r][k4*4]);
      acc[r][0] = fmaf(x4.x, w0.x, fmaf(x4.y, w0.y, fmaf(x4.z, w0.z, fmaf(x4.w, w0.w, acc[r][0]))));
      acc[r][1] = fmaf(x4.x, w1.x, fmaf(x4.y, w1.y, fmaf(x4.z, w1.z, fmaf(x4.w, w1.w, acc[r][1]))));
    }
  }
  #pragma unroll
  for (int r = 0; r < 8; r++) {
    size_t row = row0 + rg*8 + r;
    *reinterpret_cast<float2*>(&hout[row*HH + 2*ct]) = make_float2(acc[r][0], acc[r][1]);
    size_t bb = row >> 13, l = row & 8191;
    hT[((size_t)bb*HH + 2*ct  )*LL + l] = (half_t)acc[r][0];
    hT[((size_t)bb*HH + 2*ct+1)*LL + l] = (half_t)acc[r][1];
  }
}

// ---------------- kP2: per-layer SSM params -> wb (w), wl (w^64), Amat f16 [h][64 l][192 k] ----------------
// Amat k<64: Toeplitz T[l][m] = Ktap[l-m] (0 if m>l); k>=64: G[l][2n]=2Re(C~ w^{l+1}), G[l][2n+1]=-2Im.
__global__ __launch_bounds__(256) void kP2(const float* __restrict__ logdt,
   const float* __restrict__ logA, const float* __restrict__ Aim,
   const float* __restrict__ Cre, const float* __restrict__ Cim, int layer,
   float* __restrict__ wb, float* __restrict__ wl, half_t* __restrict__ Amat) {
  __shared__ float ktap[4][64];
  int t = threadIdx.x;
  int w = t >> 6;                 // wave = local h
  int n = t & 63;
  int h = blockIdx.x*4 + w;
  float dt = expf(logdt[layer*HH + h]);
  int idx = (layer*HH + h)*NN + n;
  float ar = -expf(logA[idx]);
  float ai = Aim[idx];
  float er = expf(dt*ar);
  float wr = er*cosf(dt*ai), wi = er*sinf(dt*ai);   // w = exp(dt*A)
  float inv = 1.f/(ar*ar + ai*ai);
  float mr = wr - 1.f, mi = wi;                     // expm1(dtA)
  float tr = (mr*ar + mi*ai)*inv;                   // expm1(dtA)/A
  float ti = (mi*ar - mr*ai)*inv;
  float c0 = Cre[idx], c1 = Cim[idx];
  float cr = c0*tr - c1*ti, ci = c0*ti + c1*tr;     // C_eff
  wb[(h*NN+n)*2] = wr; wb[(h*NN+n)*2+1] = wi;
  float pr = 1.f, pi = 0.f;                         // w^d
  float qr = cr*wr - ci*wi, qi = cr*wi + ci*wr;     // C~ w^{d+1}
  half_t* Ah = Amat + (size_t)h*64*192;
  for (int d = 0; d < 64; d++) {
    float kd = cr*pr - ci*pi;                       // Re(C~ w^d)
    kd += __shfl_xor(kd, 1);  kd += __shfl_xor(kd, 2);  kd += __shfl_xor(kd, 4);
    kd += __shfl_xor(kd, 8);  kd += __shfl_xor(kd, 16); kd += __shfl_xor(kd, 32);
    if (n == 0) ktap[w][d] = 2.f*kd;
    Ah[(size_t)d*192 + 64 + 2*n]   = (half_t)(2.f*qr);
    Ah[(size_t)d*192 + 64 + 2*n+1] = (half_t)(-2.f*qi);
    float npr = pr*wr - pi*wi, npi = pr*wi + pi*wr; pr = npr; pi = npi;
    float nqr = qr*wr - qi*wi, nqi = qr*wi + qi*wr; qr = nqr; qi = nqi;
  }
  wl[(h*NN+n)*2] = pr; wl[(h*NN+n)*2+1] = pi;       // w^64
  __syncthreads();
  {
    int l = n;
    half_t* row = Ah + (size_t)l*192;
    for (int m = 0; m < 64; m++)
      row[m] = (half_t)((m <= l) ? ktap[w][l - m] : 0.f);
  }
}

// ---------------- kG1: states GEMM + in-LDS scan -> SinitB f16 [h][b][c][128 n2] ----------------
// S_local_end[n2][c] = V[n2][m] . U[m][c];  then scan over c with w^64; SinitB = state BEFORE chunk c.
// MFMA layouts: A row=lane&15, k=(lane>>4)*8+i (row-major [M][K] LDS); B col=lane&15 same k (B^T [N][K] LDS);
// D col=lane&15, row=(lane>>4)*4+reg (m89-verified).
__global__ __launch_bounds__(256) void kG1(const half_t* __restrict__ hT,
      const float* __restrict__ wb, const float* __restrict__ wl,
      half_t* __restrict__ SinitB) {
  __shared__ float smem[17408];                     // 69632 B: va+ub then reused as s2
  half_t* va = (half_t*)smem;                       // [128 n2][72]
  half_t* ub = va + 128*72;                         // [128 c][72]
  float*  s2 = smem;                                // [128 n2][132] (reuse after barrier)
  int t = threadIdx.x;
  int h = blockIdx.x >> 3, b = blockIdx.x & 7;
  // V build: V[2n][m]=Re(w^{63-m}), V[2n+1][m]=Im(w^{63-m})
  {
    int n = t >> 2, q4 = t & 3;
    float wr = wb[(h*NN+n)*2], wi = wb[(h*NN+n)*2+1];
    float ar = wr, ai = wi;
    #pragma unroll
    for (int i = 0; i < 4; i++) { float nr = ar*ar - ai*ai, ni = 2.f*ar*ai; ar = nr; ai = ni; } // w^16
    float pr = 1.f, pi = 0.f;
    for (int e = 0; e < 3 - q4; e++) { float nr = pr*ar - pi*ai, ni = pr*ai + pi*ar; pr = nr; pi = ni; }
    int k0 = (3 - q4)*16;
    for (int i = 0; i < 16; i++) {
      int m = 63 - (k0 + i);
      va[(2*n)*72 + m]   = (half_t)pr;
      va[(2*n+1)*72 + m] = (half_t)pi;
      float nr = pr*wr - pi*wi, ni = pr*wi + pi*wr; pr = nr; pi = ni;
    }
  }
  // U stage: ub[c][m] <- hT[b][h][c*64+m]
  {
    const half_t* src = hT + ((size_t)b*HH + h)*LL;
    #pragma unroll
    for (int i = 0; i < 4; i++) {
      int idx = t + i*256;
      int row = idx >> 3, off = (idx & 7)*8;
      *(f16x8_t*)&ub[row*72 + off] = *(const f16x8_t*)&src[row*64 + off];
    }
  }
  __syncthreads();
  int wid = t >> 6, lane = t & 63;
  int wr_ = wid >> 1, wc = wid & 1;
  int lr = lane & 15, lk = (lane >> 4)*8;
  f32x4_t acc[4][4];
  #pragma unroll
  for (int mr = 0; mr < 4; mr++)
    #pragma unroll
    for (int nc = 0; nc < 4; nc++) acc[mr][nc] = (f32x4_t){0.f,0.f,0.f,0.f};
  #pragma unroll
  for (int ks = 0; ks < 2; ks++) {
    int k = ks*32 + lk;
    f16x8_t af[4], bf[4];
    #pragma unroll
    for (int mr = 0; mr < 4; mr++) af[mr] = *(const f16x8_t*)&va[(wr_*64 + mr*16 + lr)*72 + k];
    #pragma unroll
    for (int nc = 0; nc < 4; nc++) bf[nc] = *(const f16x8_t*)&ub[(wc*64 + nc*16 + lr)*72 + k];
    #pragma unroll
    for (int mr = 0; mr < 4; mr++)
      #pragma unroll
      for (int nc = 0; nc < 4; nc++)
        acc[mr][nc] = __builtin_amdgcn_mfma_f32_16x16x32_f16(af[mr], bf[nc], acc[mr][nc], 0, 0, 0);
  }
  __syncthreads();                                  // frag reads done before s2 overwrite
  #pragma unroll
  for (int mr = 0; mr < 4; mr++)
    #pragma unroll
    for (int nc = 0; nc < 4; nc++)
      #pragma unroll
      for (int r = 0; r < 4; r++)
        s2[(wr_*64 + mr*16 + (lane>>4)*4 + r)*132 + (wc*64 + nc*16 + lr)] = acc[mr][nc][r];
  __syncthreads();
  if (t < 64) {                                     // serial scan over chunks (1 wave)
    int n = t;
    float w64r = wl[(h*NN+n)*2], w64i = wl[(h*NN+n)*2+1];
    float cr = 0.f, ci = 0.f;
    for (int c = 0; c < NC; c++) {
      float lre = s2[(2*n)*132 + c], lim = s2[(2*n+1)*132 + c];
      s2[(2*n)*132 + c] = cr; s2[(2*n+1)*132 + c] = ci;
      float nr = w64r*cr - w64i*ci + lre;
      float ni = w64i*cr + w64r*ci + lim;
      cr = nr; ci = ni;
    }
  }
  __syncthreads();
  {
    int c = t >> 1, hf = t & 1;
    half_t* dst = SinitB + (((size_t)h*BB + b)*NC + c)*128 + hf*64;
    for (int i = 0; i < 64; i += 4) {
      f16x4_t v = { (half_t)s2[(hf*64+i  )*132 + c], (half_t)s2[(hf*64+i+1)*132 + c],
                    (half_t)s2[(hf*64+i+2)*132 + c], (half_t)s2[(hf*64+i+3)*132 + c] };
      *(f16x4_t*)&dst[i] = v;
    }
  }
}

// ---------------- kG2: output GEMM  y[l][c] = [T|G][l][k] . [U;Sinit][k][c]  -> yT f16 [b][h][l] ----------------
__global__ __launch_bounds__(256) void kG2(const half_t* __restrict__ hT,
      const half_t* __restrict__ SinitB, const half_t* __restrict__ Amat,
      half_t* __restrict__ yT) {
  __shared__ half_t As[64*200];                     // 25600 B
  __shared__ half_t Bs[128*200];                    // 51200 B
  int t = threadIdx.x;
  int h = blockIdx.x >> 3, b = blockIdx.x & 7;
  const half_t* Ag = Amat + (size_t)h*64*192;
  #pragma unroll
  for (int i = 0; i < 6; i++) {
    int idx = t + i*256;                            // < 1536
    int row = idx / 24, s8 = (idx % 24)*8;
    *(f16x8_t*)&As[row*200 + s8] = *(const f16x8_t*)&Ag[(size_t)row*192 + s8];
  }
  const half_t* Ug = hT + ((size_t)b*HH + h)*LL;
  const half_t* Sg = SinitB + ((size_t)h*BB + b)*NC*128;
  #pragma unroll
  for (int i = 0; i < 12; i++) {
    int idx = t + i*256;                            // < 3072
    int row = idx / 24, seg = idx % 24;
    f16x8_t v;
    if (seg < 8) v = *(const f16x8_t*)&Ug[row*64 + seg*8];
    else         v = *(const f16x8_t*)&Sg[row*128 + (seg-8)*8];
    *(f16x8_t*)&Bs[row*200 + seg*8] = v;
  }
  __syncthreads();
  int wc = t >> 6, lane = t & 63;
  int lr = lane & 15, lk = (lane >> 4)*8;
  f32x4_t acc[4][2];
  #pragma unroll
  for (int mr = 0; mr < 4; mr++) { acc[mr][0] = (f32x4_t){0.f,0.f,0.f,0.f}; acc[mr][1] = (f32x4_t){0.f,0.f,0.f,0.f}; }
  #pragma unroll
  for (int ks = 0; ks < 6; ks++) {
    int k = ks*32 + lk;
    f16x8_t af[4], bf[2];
    #pragma unroll
    for (int mr = 0; mr < 4; mr++) af[mr] = *(const f16x8_t*)&As[(mr*16 + lr)*200 + k];
    #pragma unroll
    for (int nc = 0; nc < 2; nc++) bf[nc] = *(const f16x8_t*)&Bs[(wc*32 + nc*16 + lr)*200 + k];
    #pragma unroll
    for (int mr = 0; mr < 4; mr++)
      #pragma unroll
      for (int nc = 0; nc < 2; nc++)
        acc[mr][nc] = __builtin_amdgcn_mfma_f32_16x16x32_f16(af[mr], bf[nc], acc[mr][nc], 0, 0, 0);
  }
  half_t* yp = yT + ((size_t)b*HH + h)*LL;
  #pragma unroll
  for (int mr = 0; mr < 4; mr++)
    #pragma unroll
    for (int nc = 0; nc < 2; nc++) {
      int c  = wc*32 + nc*16 + lr;
      int l0 = mr*16 + (lane>>4)*4;
      f16x4_t v = { (half_t)acc[mr][nc][0], (half_t)acc[mr][nc][1],
                    (half_t)acc[mr][nc][2], (half_t)acc[mr][nc][3] };
      *(f16x4_t*)&yp[c*64 + l0] = v;
    }
}

// ---------------- kD: skip + gelu + GLU + residual + rmsnorm (IN-PLACE on h) + hT dual-write ----------------
// hout == hin is safe: all hin reads (stages 1b,3) precede stage-5 writes; blocks own disjoint rows.
__global__ __launch_bounds__(256) void kD(const half_t* __restrict__ yT,
     const float* __restrict__ hin, const float* __restrict__ dskip,
     const float4* __restrict__ wpk4, const float* __restrict__ bglu,
     float* __restrict__ hout, half_t* __restrict__ hT) {
  __shared__ float yy[32][HH+4];                    // pad 132 for transposed fills
  __shared__ float rnorm[32];
  size_t row0 = (size_t)blockIdx.x * 32;
  int b = (int)(row0 >> 13);
  int l0 = (int)(row0 & 8191);
  int t = threadIdx.x;
  // stage 1a: yT [b][h][l] -> yy[l][h]
  {
    int h = t & 127, hf = t >> 7;
    const half_t* yp = yT + ((size_t)b*HH + h)*LL + l0 + hf*16;
    f16x8_t v0 = *(const f16x8_t*)yp;
    f16x8_t v1 = *(const f16x8_t*)(yp + 8);
    #pragma unroll
    for (int i = 0; i < 8; i++) yy[hf*16 + i][h]     = (float)v0[i];
    #pragma unroll
    for (int i = 0; i < 8; i++) yy[hf*16 + 8 + i][h] = (float)v1[i];
  }
  __syncthreads();
  // stage 1b: v = y + u*D_skip; yy = gelu(v)
  #pragma unroll
  for (int k = 0; k < 4; k++) {
    int idx = t + k*256;
    int r = idx >> 5, c4 = idx & 31;
    const float4 u4 = *reinterpret_cast<const float4*>(&hin[(row0 + r)*HH + c4*4]);
    const float4 d4 = *reinterpret_cast<const float4*>(&dskip[c4*4]);
    float4 y4 = *reinterpret_cast<const float4*>(&yy[r][c4*4]);
    float v[4] = { fmaf(u4.x, d4.x, y4.x), fmaf(u4.y, d4.y, y4.y),
                   fmaf(u4.z, d4.z, y4.z), fmaf(u4.w, d4.w, y4.w) };
    float o[4];
    #pragma unroll
    for (int q = 0; q < 4; q++) {
      float vv = v[q];
      float arg = 0.7978845608028654f*(vv + 0.044715f*vv*vv*vv);
      arg = fminf(fmaxf(arg, -15.f), 15.f);
      float e = __expf(2.f*arg);
      float th = (e - 1.f)/(e + 1.f);
      o[q] = 0.5f*vv*(1.f + th);
    }
    *reinterpret_cast<float4*>(&yy[r][c4*4]) = make_float4(o[0], o[1], o[2], o[3]);
  }
  __syncthreads();
  // stage 2: GLU matmul (paired-col weights)
  int ct = t & 63, rg = t >> 6;
  float acc[8][4];
  {
    float b0 = bglu[2*ct], b1 = bglu[2*ct+1], b2 = bglu[2*ct+128], b3 = bglu[2*ct+129];
    #pragma unroll
    for (int r = 0; r < 8; r++) { acc[r][0] = b0; acc[r][1] = b1; acc[r][2] = b2; acc[r][3] = b3; }
  }
  for (int h4 = 0; h4 < 32; h4++) {
    float4 w0 = wpk4[(h4*4+0)*64 + ct];
    float4 w1 = wpk4[(h4*4+1)*64 + ct];
    float4 w2 = wpk4[(h4*4+2)*64 + ct];
    float4 w3 = wpk4[(h4*4+3)*64 + ct];
    #pragma unroll
    for (int r = 0; r < 8; r++) {
      const float4 y4 = *reinterpret_cast<const float4*>(&yy[rg*8 + r][h4*4]);
      acc[r][0] = fmaf(y4.x, w0.x, fmaf(y4.y, w1.x, fmaf(y4.z, w2.x, fmaf(y4.w, w3.x, acc[r][0]))));
      acc[r][1] = fmaf(y4.x, w0.y, fmaf(y4.y, w1.y, fmaf(y4.z, w2.y, fmaf(y4.w, w3.y, acc[r][1]))));
      acc[r][2] = fmaf(y4.x, w0.z, fmaf(y4.y, w1.z, fmaf(y4.z, w2.z, fmaf(y4.w, w3.z, acc[r][2]))));
      acc[r][3] = fmaf(y4.x, w0.w, fmaf(y4.y, w1.w, fmaf(y4.z, w2.w, fmaf(y4.w, w3.w, acc[r][3]))));
    }
  }
  __syncthreads();
  // stage 3: a*sigmoid(g) + residual -> yy
  #pragma unroll
  for (int r = 0; r < 8; r++) {
    size_t grow = row0 + rg*8 + r;
    const float2 res = *reinterpret_cast<const float2*>(&hin[grow*HH + 2*ct]);
    float s0 = 1.f/(1.f + __expf(-acc[r][2]));
    float s1 = 1.f/(1.f + __expf(-acc[r][3]));
    yy[rg*8 + r][2*ct]   = fmaf(acc[r][0], s0, res.x);
    yy[rg*8 + r][2*ct+1] = fmaf(acc[r][1], s1, res.y);
  }
  __syncthreads();
  // stage 4: row 2-norms
  #pragma unroll
  for (int i = 0; i < 4; i++) {
    int idx = i*256 + t;
    int row = idx >> 5, c4 = idx & 31;
    const float4 f = *reinterpret_cast<const float4*>(&yy[row][c4*4]);
    float s = fmaf(f.x, f.x, fmaf(f.y, f.y, fmaf(f.z, f.z, f.w*f.w)));
    s += __shfl_xor(s, 1); s += __shfl_xor(s, 2); s += __shfl_xor(s, 4);
    s += __shfl_xor(s, 8); s += __shfl_xor(s, 16);
    if ((t & 31) == 0) rnorm[row] = s;
  }
  __syncthreads();
  // stage 5: normalize + write fp32 (in-place) + f16 transposed
  #pragma unroll
  for (int k = 0; k < 4; k++) {
    int idx = t + k*256;
    int r = idx >> 5, c4 = idx & 31;
    float scale = 11.313708498984761f / fmaxf(sqrtf(rnorm[r]), 1e-12f);
    float4 f = *reinterpret_cast<const float4*>(&yy[r][c4*4]);
    f.x *= scale; f.y *= scale; f.z *= scale; f.w *= scale;
    *reinterpret_cast<float4*>(&hout[(row0 + r)*HH + c4*4]) = f;
    int lglob = l0 + r;
    half_t* hb = hT + (size_t)b*HH*LL;
    hb[(size_t)(c4*4+0)*LL + lglob] = (half_t)f.x;
    hb[(size_t)(c4*4+1)*LL + lglob] = (half_t)f.y;
    hb[(size_t)(c4*4+2)*LL + lglob] = (half_t)f.z;
    hb[(size_t)(c4*4+3)*LL + lglob] = (half_t)f.w;
  }
}

// ---------------- kE: out = h @ W_out + b_out ----------------
__global__ __launch_bounds__(256) void kE(const float* __restrict__ hin,
      const float4* __restrict__ wo4, const float* __restrict__ bout,
      float* __restrict__ out) {
  __shared__ float hs[64][HH];
  size_t row0 = (size_t)blockIdx.x * 64;
  int t = threadIdx.x;
  #pragma unroll
  for (int k = 0; k < 8; k++) {
    int idx = t + k*256;
    int r = idx >> 5, c4 = idx & 31;
    *reinterpret_cast<float4*>(&hs[r][c4*4]) =
        *reinterpret_cast<const float4*>(&hin[(row0 + r)*HH + c4*4]);
  }
  __syncthreads();
  int ct = t & 31, rg = t >> 5;
  float acc[8][2];
  float b0 = bout[2*ct], b1 = bout[2*ct+1];
  #pragma unroll
  for (int r = 0; r < 8; r++) { acc[r][0] = b0; acc[r][1] = b1; }
  for (int h4 = 0; h4 < 32; h4++) {
    float4 w0 = wo4[h4*64 + 2*ct];
    float4 w1 = wo4[h4*64 + 2*ct+1];
    #pragma unroll
    for (int r = 0; r < 8; r++) {
      const float4 h4v = *reinterpret_cast<const float4*>(&hs[rg*8 + r][h4*4]);
      acc[r][0] = fmaf(h4v.x, w0.x, fmaf(h4v.y, w0.y, fmaf(h4v.z, w0.z, fmaf(h4v.w, w0.w, acc[r][0]))));
      acc[r][1] = fmaf(h4v.x, w1.x, fmaf(h4v.y, w1.y, fmaf(h4v.z, w1.z, fmaf(h4v.w, w1.w, acc[r][1]))));
    }
  }
  #pragma unroll
  for (int r = 0; r < 8; r++) {
    float2 v = make_float2(acc[r][0], acc[r][1]);
    *reinterpret_cast<float2*>(&out[(row0 + rg*8 + r)*DD + 2*ct]) = v;
  }
}

extern "C" void kernel_launch(void* const* d_in, const int* in_sizes, int n_in,
                              void* d_out, int out_size, void* d_ws, size_t ws_size,
                              hipStream_t stream) {
  const float* x     = (const float*)d_in[0];
  const float* Win   = (const float*)d_in[1];
  const float* bin   = (const float*)d_in[2];
  const float* logdt = (const float*)d_in[3];
  const float* logA  = (const float*)d_in[4];
  const float* Aim   = (const float*)d_in[5];
  const float* Cre   = (const float*)d_in[6];
  const float* Cim   = (const float*)d_in[7];
  const float* Dsk   = (const float*)d_in[8];
  const float* Wglu  = (const float*)d_in[9];
  const float* bglu  = (const float*)d_in[10];
  const float* Wout  = (const float*)d_in[11];
  const float* bout  = (const float*)d_in[12];
  float* out = (float*)d_out;

  float* ws   = (float*)d_ws;
  float* wb   = ws;                         // 16384
  float* wl   = wb  + SZ_WB;                // 16384
  float* wg4  = wl  + SZ_WL;                // 98304
  float* wo4  = wg4 + SZ_WG4;               // 8192
  float* wi4  = wo4 + SZ_WO4;               // 8192
  float* amF  = wi4 + SZ_WI4;               // Amat f16: 786432 float-units
  float* sbF  = amF + SZ_AM;                // SinitB f16: 8388608
  float* htF  = sbF + SZ_SB;                // hT f16: 4194304
  float* ytF  = htF + SZ_HT;                // yT f16: 4194304
  float* hA   = ytF + SZ_YT;                // fp32 stream: 8388608
  // total = 26,099,712 floats = 104.4 MB (< 118 MB proven available)
  half_t* Amat   = (half_t*)amF;
  half_t* SinitB = (half_t*)sbF;
  half_t* hT     = (half_t*)htF;
  half_t* yT     = (half_t*)ytF;

  kW1<<<dim3(96), dim3(256), 0, stream>>>(Wglu, (float4*)wg4);
  kW2<<<dim3(8),  dim3(256), 0, stream>>>(Wout, (float4*)wo4);
  kW3<<<dim3(8),  dim3(256), 0, stream>>>(Win,  (float4*)wi4);
  kIn<<<dim3(2048), dim3(256), 0, stream>>>(x, (const float4*)wi4, bin, hA, hT);

  for (int layer = 0; layer < NLAYER; ++layer) {
    kP2<<<dim3(32),   dim3(256), 0, stream>>>(logdt, logA, Aim, Cre, Cim, layer, wb, wl, Amat);
    kG1<<<dim3(1024), dim3(256), 0, stream>>>(hT, wb, wl, SinitB);
    kG2<<<dim3(1024), dim3(256), 0, stream>>>(hT, SinitB, Amat, yT);
    kD <<<dim3(2048), dim3(256), 0, stream>>>(yT, hA, Dsk + layer*HH,
                       (const float4*)(wg4 + (size_t)layer*HH*64*4),
                       bglu + layer*2*HH, hA, hT);
  }
  kE<<<dim3(1024), dim3(256), 0, stream>>>(hA, (const float4*)wo4, bout, out);
}

// Round 8
// 501.752 us; speedup vs baseline: 1.4001x; 1.1057x over previous
//
#include <hip/hip_runtime.h>
#include <math.h>

#define BB 8
#define LL 8192
#define DD 64
#define HH 128
#define NN 64
#define NLAYER 3
#define LC 64          // chunk length
#define NC 128         // chunks per (b,h) sequence

typedef _Float16 half_t;
typedef _Float16 f16x8_t __attribute__((ext_vector_type(8)));
typedef _Float16 f16x4_t __attribute__((ext_vector_type(4)));
typedef float    f32x4_t __attribute__((ext_vector_type(4)));

// workspace sizes in float units
#define SZ_WB   ((size_t)HH*NN*2)            // 16384 (w complex fp32)
#define SZ_WL   ((size_t)HH*NN*2)            // 16384 (w^64 complex fp32)
#define SZ_WG4  ((size_t)NLAYER*HH*64*4)     // 98304
#define SZ_WO4  ((size_t)32*64*4)            // 8192
#define SZ_WI4  ((size_t)16*128*4)           // 8192
#define SZ_AM   ((size_t)HH*64*192/2)        // 786432  (f16 [h][64 l][192 k])
#define SZ_SB   ((size_t)HH*BB*NC*128/2)     // 8388608 (f16 [h][b][c][128 n2])
#define SZ_HT   ((size_t)BB*HH*LL/2)         // 4194304 (f16 [b][h][l])
#define SZ_YT   ((size_t)BB*HH*LL/2)         // 4194304 (f16 [b][h][l])
#define SZ_H    ((size_t)BB*LL*HH)           // 8388608 (fp32 residual stream)

// ---------------- weight repack kernels ----------------
__global__ __launch_bounds__(256) void kW1(const float* __restrict__ Wglu,
                                           float4* __restrict__ wpk4) {
  int tid = blockIdx.x*256 + threadIdx.x;        // < 3*128*64
  int l   = tid >> 13;
  int rem = tid & 8191;
  int h   = rem >> 6;
  int ct  = rem & 63;
  const float* base = Wglu + (size_t)l*256*128 + h;
  wpk4[tid] = make_float4(base[(2*ct)*128], base[(2*ct+1)*128],
                          base[(2*ct+128)*128], base[(2*ct+129)*128]);
}
__global__ __launch_bounds__(256) void kW2(const float* __restrict__ Wout,
                                           float4* __restrict__ wo4) {
  int tid = blockIdx.x*256 + threadIdx.x;        // < 2048
  int h4 = tid >> 6, d = tid & 63;
  wo4[tid] = make_float4(Wout[(4*h4+0)*DD + d], Wout[(4*h4+1)*DD + d],
                         Wout[(4*h4+2)*DD + d], Wout[(4*h4+3)*DD + d]);
}
__global__ __launch_bounds__(256) void kW3(const float* __restrict__ Win,
                                           float4* __restrict__ wip4) {
  int tid = blockIdx.x*256 + threadIdx.x;        // < 2048
  int k4 = tid >> 7, col = tid & 127;
  wip4[tid] = make_float4(Win[(4*k4+0)*HH + col], Win[(4*k4+1)*HH + col],
                          Win[(4*k4+2)*HH + col], Win[(4*k4+3)*HH + col]);
}

// ---------------- kIn: h = x @ W_in + b_in ; dual-write fp32 (b,l,h) + f16 [b][h][l] ----------------
__global__ __launch_bounds__(256) void kIn(const float* __restrict__ x,
      const float4* __restrict__ wip4, const float* __restrict__ bin,
      float* __restrict__ hout, half_t* __restrict__ hT) {
  __shared__ float xs[32][DD];
  size_t row0 = (size_t)blockIdx.x * 32;
  int t = threadIdx.x;
  #pragma unroll
  for (int k = 0; k < 2; k++) {
    int idx = t + k*256;
    int r = idx >> 4, c4 = idx & 15;
    *reinterpret_cast<float4*>(&xs[r][c4*4]) =
        *reinterpret_cast<const float4*>(&x[(row0 + r)*DD + c4*4]);
  }
  __syncthreads();
  int ct = t & 63, rg = t >> 6;
  float acc[8][2];
  float b0 = bin[2*ct], b1 = bin[2*ct+1];
  #pragma unroll
  for (int r = 0; r < 8; r++) { acc[r][0] = b0; acc[r][1] = b1; }
  for (int k4 = 0; k4 < 16; k4++) {
    float4 w0 = wip4[k4*128 + 2*ct];
    float4 w1 = wip4[k4*128 + 2*ct+1];
    #pragma unroll
    for (int r = 0; r < 8; r++) {
      const float4 x4 = *reinterpret_cast<const float4*>(&xs[rg*8 + r][k4*4]);
      acc[r][0] = fmaf(x4.x, w0.x, fmaf(x4.y, w0.y, fmaf(x4.z, w0.z, fmaf(x4.w, w0.w, acc[r][0]))));
      acc[r][1] = fmaf(x4.x, w1.x, fmaf(x4.y, w1.y, fmaf(x4.z, w1.z, fmaf(x4.w, w1.w, acc[r][1]))));
    }
  }
  size_t bb = row0 >> 13;
  int l0 = (int)(row0 & 8191) + rg*8;
  f16x8_t o0, o1;
  #pragma unroll
  for (int r = 0; r < 8; r++) {
    *reinterpret_cast<float2*>(&hout[(row0 + rg*8 + r)*HH + 2*ct]) = make_float2(acc[r][0], acc[r][1]);
    o0[r] = (half_t)acc[r][0];
    o1[r] = (half_t)acc[r][1];
  }
  *(f16x8_t*)&hT[((size_t)bb*HH + 2*ct  )*LL + l0] = o0;
  *(f16x8_t*)&hT[((size_t)bb*HH + 2*ct+1)*LL + l0] = o1;
}

// ---------------- kP2: per-layer SSM params -> wb (w), wl (w^64), Amat f16 [h][64 l][192 k] ----------------
__global__ __launch_bounds__(256) void kP2(const float* __restrict__ logdt,
   const float* __restrict__ logA, const float* __restrict__ Aim,
   const float* __restrict__ Cre, const float* __restrict__ Cim, int layer,
   float* __restrict__ wb, float* __restrict__ wl, half_t* __restrict__ Amat) {
  __shared__ float ktap[4][64];
  int t = threadIdx.x;
  int w = t >> 6;                 // wave = local h
  int n = t & 63;
  int h = blockIdx.x*4 + w;
  float dt = expf(logdt[layer*HH + h]);
  int idx = (layer*HH + h)*NN + n;
  float ar = -expf(logA[idx]);
  float ai = Aim[idx];
  float er = expf(dt*ar);
  float wr = er*cosf(dt*ai), wi = er*sinf(dt*ai);   // w = exp(dt*A)
  float inv = 1.f/(ar*ar + ai*ai);
  float mr = wr - 1.f, mi = wi;                     // expm1(dtA)
  float tr = (mr*ar + mi*ai)*inv;                   // expm1(dtA)/A
  float ti = (mi*ar - mr*ai)*inv;
  float c0 = Cre[idx], c1 = Cim[idx];
  float cr = c0*tr - c1*ti, ci = c0*ti + c1*tr;     // C_eff
  wb[(h*NN+n)*2] = wr; wb[(h*NN+n)*2+1] = wi;
  float pr = 1.f, pi = 0.f;                         // w^d
  float qr = cr*wr - ci*wi, qi = cr*wi + ci*wr;     // C~ w^{d+1}
  half_t* Ah = Amat + (size_t)h*64*192;
  for (int d = 0; d < 64; d++) {
    float kd = cr*pr - ci*pi;                       // Re(C~ w^d)
    kd += __shfl_xor(kd, 1);  kd += __shfl_xor(kd, 2);  kd += __shfl_xor(kd, 4);
    kd += __shfl_xor(kd, 8);  kd += __shfl_xor(kd, 16); kd += __shfl_xor(kd, 32);
    if (n == 0) ktap[w][d] = 2.f*kd;
    Ah[(size_t)d*192 + 64 + 2*n]   = (half_t)(2.f*qr);
    Ah[(size_t)d*192 + 64 + 2*n+1] = (half_t)(-2.f*qi);
    float npr = pr*wr - pi*wi, npi = pr*wi + pi*wr; pr = npr; pi = npi;
    float nqr = qr*wr - qi*wi, nqi = qr*wi + qi*wr; qr = nqr; qi = nqi;
  }
  wl[(h*NN+n)*2] = pr; wl[(h*NN+n)*2+1] = pi;       // w^64
  __syncthreads();
  {
    int l = n;
    half_t* row = Ah + (size_t)l*192;
    for (int m = 0; m < 64; m++)
      row[m] = (half_t)((m <= l) ? ktap[w][l - m] : 0.f);
  }
}

// ---------------- kG1: states GEMM + in-LDS scan -> SinitB f16 [h][b][c][128 n2] ----------------
__global__ __launch_bounds__(256) void kG1(const half_t* __restrict__ hT,
      const float* __restrict__ wb, const float* __restrict__ wl,
      half_t* __restrict__ SinitB) {
  __shared__ float smem[17408];                     // 69632 B: va+ub then reused as s2
  half_t* va = (half_t*)smem;                       // [128 n2][72]
  half_t* ub = va + 128*72;                         // [128 c][72]
  float*  s2 = smem;                                // [128 n2][132] (reuse after barrier)
  int t = threadIdx.x;
  int h = blockIdx.x >> 3, b = blockIdx.x & 7;
  // V build: V[2n][m]=Re(w^{63-m}), V[2n+1][m]=Im(w^{63-m})
  {
    int n = t >> 2, q4 = t & 3;
    float wr = wb[(h*NN+n)*2], wi = wb[(h*NN+n)*2+1];
    float ar = wr, ai = wi;
    #pragma unroll
    for (int i = 0; i < 4; i++) { float nr = ar*ar - ai*ai, ni = 2.f*ar*ai; ar = nr; ai = ni; } // w^16
    float pr = 1.f, pi = 0.f;
    for (int e = 0; e < 3 - q4; e++) { float nr = pr*ar - pi*ai, ni = pr*ai + pi*ar; pr = nr; pi = ni; }
    int k0 = (3 - q4)*16;
    for (int i = 0; i < 16; i++) {
      int m = 63 - (k0 + i);
      va[(2*n)*72 + m]   = (half_t)pr;
      va[(2*n+1)*72 + m] = (half_t)pi;
      float nr = pr*wr - pi*wi, ni = pr*wi + pi*wr; pr = nr; pi = ni;
    }
  }
  // U stage: ub[c][m] <- hT[b][h][c*64+m]
  {
    const half_t* src = hT + ((size_t)b*HH + h)*LL;
    #pragma unroll
    for (int i = 0; i < 4; i++) {
      int idx = t + i*256;
      int row = idx >> 3, off = (idx & 7)*8;
      *(f16x8_t*)&ub[row*72 + off] = *(const f16x8_t*)&src[row*64 + off];
    }
  }
  __syncthreads();
  int wid = t >> 6, lane = t & 63;
  int wr_ = wid >> 1, wc = wid & 1;
  int lr = lane & 15, lk = (lane >> 4)*8;
  f32x4_t acc[4][4];
  #pragma unroll
  for (int mr = 0; mr < 4; mr++)
    #pragma unroll
    for (int nc = 0; nc < 4; nc++) acc[mr][nc] = (f32x4_t){0.f,0.f,0.f,0.f};
  #pragma unroll
  for (int ks = 0; ks < 2; ks++) {
    int k = ks*32 + lk;
    f16x8_t af[4], bf[4];
    #pragma unroll
    for (int mr = 0; mr < 4; mr++) af[mr] = *(const f16x8_t*)&va[(wr_*64 + mr*16 + lr)*72 + k];
    #pragma unroll
    for (int nc = 0; nc < 4; nc++) bf[nc] = *(const f16x8_t*)&ub[(wc*64 + nc*16 + lr)*72 + k];
    #pragma unroll
    for (int mr = 0; mr < 4; mr++)
      #pragma unroll
      for (int nc = 0; nc < 4; nc++)
        acc[mr][nc] = __builtin_amdgcn_mfma_f32_16x16x32_f16(af[mr], bf[nc], acc[mr][nc], 0, 0, 0);
  }
  __syncthreads();                                  // frag reads done before s2 overwrite
  #pragma unroll
  for (int mr = 0; mr < 4; mr++)
    #pragma unroll
    for (int nc = 0; nc < 4; nc++)
      #pragma unroll
      for (int r = 0; r < 4; r++)
        s2[(wr_*64 + mr*16 + (lane>>4)*4 + r)*132 + (wc*64 + nc*16 + lr)] = acc[mr][nc][r];
  __syncthreads();
  if (t < 64) {                                     // serial scan over chunks (1 wave)
    int n = t;
    float w64r = wl[(h*NN+n)*2], w64i = wl[(h*NN+n)*2+1];
    float cr = 0.f, ci = 0.f;
    #pragma unroll 4
    for (int c = 0; c < NC; c++) {
      float lre = s2[(2*n)*132 + c], lim = s2[(2*n+1)*132 + c];
      s2[(2*n)*132 + c] = cr; s2[(2*n+1)*132 + c] = ci;
      float nr = fmaf(w64r, cr, fmaf(-w64i, ci, lre));
      float ni = fmaf(w64i, cr, fmaf(w64r, ci, lim));
      cr = nr; ci = ni;
    }
  }
  __syncthreads();
  {
    int c = t >> 1, hf = t & 1;
    half_t* dst = SinitB + (((size_t)h*BB + b)*NC + c)*128 + hf*64;
    for (int i = 0; i < 64; i += 4) {
      f16x4_t v = { (half_t)s2[(hf*64+i  )*132 + c], (half_t)s2[(hf*64+i+1)*132 + c],
                    (half_t)s2[(hf*64+i+2)*132 + c], (half_t)s2[(hf*64+i+3)*132 + c] };
      *(f16x4_t*)&dst[i] = v;
    }
  }
}

// ---------------- kG2: output GEMM  y[l][c] = [T|G][l][k] . [U;Sinit][k][c]  -> yT f16 [b][h][l] ----------------
__global__ __launch_bounds__(256) void kG2(const half_t* __restrict__ hT,
      const half_t* __restrict__ SinitB, const half_t* __restrict__ Amat,
      half_t* __restrict__ yT) {
  __shared__ half_t As[64*200];                     // 25600 B
  __shared__ half_t Bs[128*200];                    // 51200 B
  int t = threadIdx.x;
  int h = blockIdx.x >> 3, b = blockIdx.x & 7;
  const half_t* Ag = Amat + (size_t)h*64*192;
  #pragma unroll
  for (int i = 0; i < 6; i++) {
    int idx = t + i*256;                            // < 1536
    int row = idx / 24, s8 = (idx % 24)*8;
    *(f16x8_t*)&As[row*200 + s8] = *(const f16x8_t*)&Ag[(size_t)row*192 + s8];
  }
  const half_t* Ug = hT + ((size_t)b*HH + h)*LL;
  const half_t* Sg = SinitB + ((size_t)h*BB + b)*NC*128;
  #pragma unroll
  for (int i = 0; i < 12; i++) {
    int idx = t + i*256;                            // < 3072
    int row = idx / 24, seg = idx % 24;
    f16x8_t v;
    if (seg < 8) v = *(const f16x8_t*)&Ug[row*64 + seg*8];
    else         v = *(const f16x8_t*)&Sg[row*128 + (seg-8)*8];
    *(f16x8_t*)&Bs[row*200 + seg*8] = v;
  }
  __syncthreads();
  int wc = t >> 6, lane = t & 63;
  int lr = lane & 15, lk = (lane >> 4)*8;
  f32x4_t acc[4][2];
  #pragma unroll
  for (int mr = 0; mr < 4; mr++) { acc[mr][0] = (f32x4_t){0.f,0.f,0.f,0.f}; acc[mr][1] = (f32x4_t){0.f,0.f,0.f,0.f}; }
  #pragma unroll
  for (int ks = 0; ks < 6; ks++) {
    int k = ks*32 + lk;
    f16x8_t af[4], bf[2];
    #pragma unroll
    for (int mr = 0; mr < 4; mr++) af[mr] = *(const f16x8_t*)&As[(mr*16 + lr)*200 + k];
    #pragma unroll
    for (int nc = 0; nc < 2; nc++) bf[nc] = *(const f16x8_t*)&Bs[(wc*32 + nc*16 + lr)*200 + k];
    #pragma unroll
    for (int mr = 0; mr < 4; mr++)
      #pragma unroll
      for (int nc = 0; nc < 2; nc++)
        acc[mr][nc] = __builtin_amdgcn_mfma_f32_16x16x32_f16(af[mr], bf[nc], acc[mr][nc], 0, 0, 0);
  }
  half_t* yp = yT + ((size_t)b*HH + h)*LL;
  #pragma unroll
  for (int mr = 0; mr < 4; mr++)
    #pragma unroll
    for (int nc = 0; nc < 2; nc++) {
      int c  = wc*32 + nc*16 + lr;
      int l0 = mr*16 + (lane>>4)*4;
      f16x4_t v = { (half_t)acc[mr][nc][0], (half_t)acc[mr][nc][1],
                    (half_t)acc[mr][nc][2], (half_t)acc[mr][nc][3] };
      *(f16x4_t*)&yp[c*64 + l0] = v;
    }
}

// ---------------- kD: skip + gelu + GLU + residual + rmsnorm (IN-PLACE on h) + hT dual-write ----------------
// Thread (ct,rg): h-pair {2ct,2ct+1}, l-range rg*8..rg*8+7. All f16 I/O is 16B-contiguous per h.
// u (hin) loaded once, kept in regs for gelu input AND residual. hout==hin safe (reads precede writes,
// disjoint rows per block). hT in-place safe (kD never reads hT).
__global__ __launch_bounds__(256) void kD(const half_t* __restrict__ yT,
     const float* __restrict__ hin, const float* __restrict__ dskip,
     const float4* __restrict__ wpk4, const float* __restrict__ bglu,
     float* __restrict__ hout, half_t* __restrict__ hT) {
  __shared__ float yy[32][HH+4];
  __shared__ float rnorm[32];
  size_t row0 = (size_t)blockIdx.x * 32;
  int b  = (int)(row0 >> 13);
  int l0 = (int)(row0 & 8191);
  int t = threadIdx.x;
  int ct = t & 63, rg = t >> 6;
  int h0 = 2*ct, h1 = 2*ct + 1;
  // ---- stage 1: load y (2x f16x8), u (8x float2); gelu -> LDS
  const half_t* yb = yT + ((size_t)b*HH)*LL + l0 + rg*8;
  f16x8_t y0 = *(const f16x8_t*)&yb[(size_t)h0*LL];
  f16x8_t y1 = *(const f16x8_t*)&yb[(size_t)h1*LL];
  float2 u[8];
  const float* ubase = hin + (row0 + rg*8)*HH + h0;
  #pragma unroll
  for (int i = 0; i < 8; i++) u[i] = *(const float2*)&ubase[(size_t)i*HH];
  float d0 = dskip[h0], d1 = dskip[h1];
  #pragma unroll
  for (int i = 0; i < 8; i++) {
    float v0 = fmaf(u[i].x, d0, (float)y0[i]);
    float v1 = fmaf(u[i].y, d1, (float)y1[i]);
    float g2[2];
    float vv[2] = {v0, v1};
    #pragma unroll
    for (int q = 0; q < 2; q++) {
      float v = vv[q];
      float arg = 0.7978845608028654f*(v + 0.044715f*v*v*v);
      arg = fminf(fmaxf(arg, -15.f), 15.f);
      float e = __expf(2.f*arg);
      float th = (e - 1.f)/(e + 1.f);
      g2[q] = 0.5f*v*(1.f + th);
    }
    *reinterpret_cast<float2*>(&yy[rg*8 + i][h0]) = make_float2(g2[0], g2[1]);
  }
  __syncthreads();
  // ---- stage 2: GLU matmul. acc[r][0..1]=a cols {2ct,2ct+1}, acc[r][2..3]=gate cols {+128}
  float acc[8][4];
  {
    float b0 = bglu[2*ct], b1 = bglu[2*ct+1], b2 = bglu[2*ct+128], b3 = bglu[2*ct+129];
    #pragma unroll
    for (int r = 0; r < 8; r++) { acc[r][0] = b0; acc[r][1] = b1; acc[r][2] = b2; acc[r][3] = b3; }
  }
  for (int h4 = 0; h4 < 32; h4++) {
    float4 w0 = wpk4[(h4*4+0)*64 + ct];
    float4 w1 = wpk4[(h4*4+1)*64 + ct];
    float4 w2 = wpk4[(h4*4+2)*64 + ct];
    float4 w3 = wpk4[(h4*4+3)*64 + ct];
    #pragma unroll
    for (int r = 0; r < 8; r++) {
      const float4 y4 = *reinterpret_cast<const float4*>(&yy[rg*8 + r][h4*4]);
      acc[r][0] = fmaf(y4.x, w0.x, fmaf(y4.y, w1.x, fmaf(y4.z, w2.x, fmaf(y4.w, w3.x, acc[r][0]))));
      acc[r][1] = fmaf(y4.x, w0.y, fmaf(y4.y, w1.y, fmaf(y4.z, w2.y, fmaf(y4.w, w3.y, acc[r][1]))));
      acc[r][2] = fmaf(y4.x, w0.z, fmaf(y4.y, w1.z, fmaf(y4.z, w2.z, fmaf(y4.w, w3.z, acc[r][2]))));
      acc[r][3] = fmaf(y4.x, w0.w, fmaf(y4.y, w1.w, fmaf(y4.z, w2.w, fmaf(y4.w, w3.w, acc[r][3]))));
    }
  }
  __syncthreads();   // all stage-2 yy reads done before overwrite
  // ---- stage 3: z = a*sigmoid(g) + residual(u regs) -> regs + LDS (for row norms)
  float2 za[8];
  #pragma unroll
  for (int r = 0; r < 8; r++) {
    float s0 = 1.f/(1.f + __expf(-acc[r][2]));
    float s1 = 1.f/(1.f + __expf(-acc[r][3]));
    za[r].x = fmaf(acc[r][0], s0, u[r].x);
    za[r].y = fmaf(acc[r][1], s1, u[r].y);
    *reinterpret_cast<float2*>(&yy[rg*8 + r][h0]) = za[r];
  }
  __syncthreads();
  // ---- stage 4: row 2-norms
  #pragma unroll
  for (int i = 0; i < 4; i++) {
    int idx = i*256 + t;
    int row = idx >> 5, c4 = idx & 31;
    const float4 f = *reinterpret_cast<const float4*>(&yy[row][c4*4]);
    float s = fmaf(f.x, f.x, fmaf(f.y, f.y, fmaf(f.z, f.z, f.w*f.w)));
    s += __shfl_xor(s, 1); s += __shfl_xor(s, 2); s += __shfl_xor(s, 4);
    s += __shfl_xor(s, 8); s += __shfl_xor(s, 16);
    if ((t & 31) == 0) rnorm[row] = s;
  }
  __syncthreads();
  // ---- stage 5: scale reg z; wide writes to hout (float2) and hT (2x f16x8)
  f16x8_t o0, o1;
  #pragma unroll
  for (int r = 0; r < 8; r++) {
    float scale = 11.313708498984761f / fmaxf(sqrtf(rnorm[rg*8 + r]), 1e-12f);
    float z0 = za[r].x*scale, z1 = za[r].y*scale;
    *reinterpret_cast<float2*>(&hout[(row0 + rg*8 + r)*HH + h0]) = make_float2(z0, z1);
    o0[r] = (half_t)z0;
    o1[r] = (half_t)z1;
  }
  half_t* hb = hT + (size_t)b*HH*LL + l0 + rg*8;
  *(f16x8_t*)&hb[(size_t)h0*LL] = o0;
  *(f16x8_t*)&hb[(size_t)h1*LL] = o1;
}

// ---------------- kE: out = h @ W_out + b_out ----------------
__global__ __launch_bounds__(256) void kE(const float* __restrict__ hin,
      const float4* __restrict__ wo4, const float* __restrict__ bout,
      float* __restrict__ out) {
  __shared__ float hs[64][HH];
  size_t row0 = (size_t)blockIdx.x * 64;
  int t = threadIdx.x;
  #pragma unroll
  for (int k = 0; k < 8; k++) {
    int idx = t + k*256;
    int r = idx >> 5, c4 = idx & 31;
    *reinterpret_cast<float4*>(&hs[r][c4*4]) =
        *reinterpret_cast<const float4*>(&hin[(row0 + r)*HH + c4*4]);
  }
  __syncthreads();
  int ct = t & 31, rg = t >> 5;
  float acc[8][2];
  float b0 = bout[2*ct], b1 = bout[2*ct+1];
  #pragma unroll
  for (int r = 0; r < 8; r++) { acc[r][0] = b0; acc[r][1] = b1; }
  for (int h4 = 0; h4 < 32; h4++) {
    float4 w0 = wo4[h4*64 + 2*ct];
    float4 w1 = wo4[h4*64 + 2*ct+1];
    #pragma unroll
    for (int r = 0; r < 8; r++) {
      const float4 h4v = *reinterpret_cast<const float4*>(&hs[rg*8 + r][h4*4]);
      acc[r][0] = fmaf(h4v.x, w0.x, fmaf(h4v.y, w0.y, fmaf(h4v.z, w0.z, fmaf(h4v.w, w0.w, acc[r][0]))));
      acc[r][1] = fmaf(h4v.x, w1.x, fmaf(h4v.y, w1.y, fmaf(h4v.z, w1.z, fmaf(h4v.w, w1.w, acc[r][1]))));
    }
  }
  #pragma unroll
  for (int r = 0; r < 8; r++) {
    float2 v = make_float2(acc[r][0], acc[r][1]);
    *reinterpret_cast<float2*>(&out[(row0 + rg*8 + r)*DD + 2*ct]) = v;
  }
}

extern "C" void kernel_launch(void* const* d_in, const int* in_sizes, int n_in,
                              void* d_out, int out_size, void* d_ws, size_t ws_size,
                              hipStream_t stream) {
  const float* x     = (const float*)d_in[0];
  const float* Win   = (const float*)d_in[1];
  const float* bin   = (const float*)d_in[2];
  const float* logdt = (const float*)d_in[3];
  const float* logA  = (const float*)d_in[4];
  const float* Aim   = (const float*)d_in[5];
  const float* Cre   = (const float*)d_in[6];
  const float* Cim   = (const float*)d_in[7];
  const float* Dsk   = (const float*)d_in[8];
  const float* Wglu  = (const float*)d_in[9];
  const float* bglu  = (const float*)d_in[10];
  const float* Wout  = (const float*)d_in[11];
  const float* bout  = (const float*)d_in[12];
  float* out = (float*)d_out;

  float* ws   = (float*)d_ws;
  float* wb   = ws;                         // 16384
  float* wl   = wb  + SZ_WB;                // 16384
  float* wg4  = wl  + SZ_WL;                // 98304
  float* wo4  = wg4 + SZ_WG4;               // 8192
  float* wi4  = wo4 + SZ_WO4;               // 8192
  float* amF  = wi4 + SZ_WI4;               // Amat f16
  float* sbF  = amF + SZ_AM;                // SinitB f16
  float* htF  = sbF + SZ_SB;                // hT f16
  float* ytF  = htF + SZ_HT;                // yT f16
  float* hA   = ytF + SZ_YT;                // fp32 stream
  // total = 26,099,712 floats = 104.4 MB
  half_t* Amat   = (half_t*)amF;
  half_t* SinitB = (half_t*)sbF;
  half_t* hT     = (half_t*)htF;
  half_t* yT     = (half_t*)ytF;

  kW1<<<dim3(96), dim3(256), 0, stream>>>(Wglu, (float4*)wg4);
  kW2<<<dim3(8),  dim3(256), 0, stream>>>(Wout, (float4*)wo4);
  kW3<<<dim3(8),  dim3(256), 0, stream>>>(Win,  (float4*)wi4);
  kIn<<<dim3(2048), dim3(256), 0, stream>>>(x, (const float4*)wi4, bin, hA, hT);

  for (int layer = 0; layer < NLAYER; ++layer) {
    kP2<<<dim3(32),   dim3(256), 0, stream>>>(logdt, logA, Aim, Cre, Cim, layer, wb, wl, Amat);
    kG1<<<dim3(1024), dim3(256), 0, stream>>>(hT, wb, wl, SinitB);
    kG2<<<dim3(1024), dim3(256), 0, stream>>>(hT, SinitB, Amat, yT);
    kD <<<dim3(2048), dim3(256), 0, stream>>>(yT, hA, Dsk + layer*HH,
                       (const float4*)(wg4 + (size_t)layer*HH*64*4),
                       bglu + layer*2*HH, hA, hT);
  }
  kE<<<dim3(1024), dim3(256), 0, stream>>>(hA, (const float4*)wo4, bout, out);
}

// Round 9
// 409.042 us; speedup vs baseline: 1.7174x; 1.2267x over previous
//
#include <hip/hip_runtime.h>
#include <math.h>

#define BB 8
#define LL 8192
#define DD 64
#define HH 128
#define NN 64
#define NLAYER 3
#define LC 64          // chunk length
#define NC 128         // chunks per (b,h) sequence

typedef _Float16 half_t;
typedef _Float16 f16x8_t __attribute__((ext_vector_type(8)));
typedef _Float16 f16x4_t __attribute__((ext_vector_type(4)));
typedef _Float16 f16x2_t __attribute__((ext_vector_type(2)));
typedef float    f32x4_t __attribute__((ext_vector_type(4)));

// workspace sizes in float units
#define SZ_WB   ((size_t)HH*NN*2)            // 16384 (w complex fp32)
#define SZ_WL   ((size_t)HH*NN*2)            // 16384 (w^64 complex fp32)
#define SZ_WGT  ((size_t)NLAYER*256*HH/2)    // 49152 (Wglu f16 [l][g][h])
#define SZ_WO4  ((size_t)32*64*4)            // 8192
#define SZ_WI4  ((size_t)16*128*4)           // 8192
#define SZ_AM   ((size_t)HH*64*192/2)        // 786432  (f16 [h][64 l][192 k])
#define SZ_SB   ((size_t)HH*BB*NC*128/2)     // 8388608 (f16 [h][b][c][128 n2])
#define SZ_HT   ((size_t)BB*HH*LL/2)         // 4194304 (f16 [b][h][l])
#define SZ_YT   ((size_t)BB*HH*LL/2)         // 4194304 (f16 [b][h][l])
#define SZ_H    ((size_t)BB*LL*HH)           // 8388608 (fp32 residual stream)

// ---------------- weight prep ----------------
// Wglu (L,256,128) fp32 -> f16, same layout ([g][h] row-major = MFMA B-operand [N][K])
__global__ __launch_bounds__(256) void kW1(const float* __restrict__ Wglu,
                                           half_t* __restrict__ wgt) {
  int tid = blockIdx.x*256 + threadIdx.x;        // < 3*256*128/8 = 12288
  const float* src = Wglu + (size_t)tid*8;
  f16x8_t v;
  #pragma unroll
  for (int i = 0; i < 8; i++) v[i] = (half_t)src[i];
  *(f16x8_t*)&wgt[(size_t)tid*8] = v;
}
__global__ __launch_bounds__(256) void kW2(const float* __restrict__ Wout,
                                           float4* __restrict__ wo4) {
  int tid = blockIdx.x*256 + threadIdx.x;        // < 2048
  int h4 = tid >> 6, d = tid & 63;
  wo4[tid] = make_float4(Wout[(4*h4+0)*DD + d], Wout[(4*h4+1)*DD + d],
                         Wout[(4*h4+2)*DD + d], Wout[(4*h4+3)*DD + d]);
}
__global__ __launch_bounds__(256) void kW3(const float* __restrict__ Win,
                                           float4* __restrict__ wip4) {
  int tid = blockIdx.x*256 + threadIdx.x;        // < 2048
  int k4 = tid >> 7, col = tid & 127;
  wip4[tid] = make_float4(Win[(4*k4+0)*HH + col], Win[(4*k4+1)*HH + col],
                          Win[(4*k4+2)*HH + col], Win[(4*k4+3)*HH + col]);
}

// ---------------- kIn: h = x @ W_in + b_in ; dual-write fp32 (b,l,h) + f16 [b][h][l] ----------------
__global__ __launch_bounds__(256) void kIn(const float* __restrict__ x,
      const float4* __restrict__ wip4, const float* __restrict__ bin,
      float* __restrict__ hout, half_t* __restrict__ hT) {
  __shared__ float xs[32][DD];
  size_t row0 = (size_t)blockIdx.x * 32;
  int t = threadIdx.x;
  #pragma unroll
  for (int k = 0; k < 2; k++) {
    int idx = t + k*256;
    int r = idx >> 4, c4 = idx & 15;
    *reinterpret_cast<float4*>(&xs[r][c4*4]) =
        *reinterpret_cast<const float4*>(&x[(row0 + r)*DD + c4*4]);
  }
  __syncthreads();
  int ct = t & 63, rg = t >> 6;
  float acc[8][2];
  float b0 = bin[2*ct], b1 = bin[2*ct+1];
  #pragma unroll
  for (int r = 0; r < 8; r++) { acc[r][0] = b0; acc[r][1] = b1; }
  for (int k4 = 0; k4 < 16; k4++) {
    float4 w0 = wip4[k4*128 + 2*ct];
    float4 w1 = wip4[k4*128 + 2*ct+1];
    #pragma unroll
    for (int r = 0; r < 8; r++) {
      const float4 x4 = *reinterpret_cast<const float4*>(&xs[rg*8 + r][k4*4]);
      acc[r][0] = fmaf(x4.x, w0.x, fmaf(x4.y, w0.y, fmaf(x4.z, w0.z, fmaf(x4.w, w0.w, acc[r][0]))));
      acc[r][1] = fmaf(x4.x, w1.x, fmaf(x4.y, w1.y, fmaf(x4.z, w1.z, fmaf(x4.w, w1.w, acc[r][1]))));
    }
  }
  size_t bb = row0 >> 13;
  int l0 = (int)(row0 & 8191) + rg*8;
  f16x8_t o0, o1;
  #pragma unroll
  for (int r = 0; r < 8; r++) {
    *reinterpret_cast<float2*>(&hout[(row0 + rg*8 + r)*HH + 2*ct]) = make_float2(acc[r][0], acc[r][1]);
    o0[r] = (half_t)acc[r][0];
    o1[r] = (half_t)acc[r][1];
  }
  *(f16x8_t*)&hT[((size_t)bb*HH + 2*ct  )*LL + l0] = o0;
  *(f16x8_t*)&hT[((size_t)bb*HH + 2*ct+1)*LL + l0] = o1;
}

// ---------------- kP2: per-layer SSM params -> wb (w), wl (w^64), Amat f16 [h][64 l][192 k] ----------------
__global__ __launch_bounds__(256) void kP2(const float* __restrict__ logdt,
   const float* __restrict__ logA, const float* __restrict__ Aim,
   const float* __restrict__ Cre, const float* __restrict__ Cim, int layer,
   float* __restrict__ wb, float* __restrict__ wl, half_t* __restrict__ Amat) {
  __shared__ float ktap[4][64];
  int t = threadIdx.x;
  int w = t >> 6;                 // wave = local h
  int n = t & 63;
  int h = blockIdx.x*4 + w;
  float dt = expf(logdt[layer*HH + h]);
  int idx = (layer*HH + h)*NN + n;
  float ar = -expf(logA[idx]);
  float ai = Aim[idx];
  float er = expf(dt*ar);
  float wr = er*cosf(dt*ai), wi = er*sinf(dt*ai);   // w = exp(dt*A)
  float inv = 1.f/(ar*ar + ai*ai);
  float mr = wr - 1.f, mi = wi;                     // expm1(dtA)
  float tr = (mr*ar + mi*ai)*inv;                   // expm1(dtA)/A
  float ti = (mi*ar - mr*ai)*inv;
  float c0 = Cre[idx], c1 = Cim[idx];
  float cr = c0*tr - c1*ti, ci = c0*ti + c1*tr;     // C_eff
  wb[(h*NN+n)*2] = wr; wb[(h*NN+n)*2+1] = wi;
  float pr = 1.f, pi = 0.f;                         // w^d
  float qr = cr*wr - ci*wi, qi = cr*wi + ci*wr;     // C~ w^{d+1}
  half_t* Ah = Amat + (size_t)h*64*192;
  for (int d = 0; d < 64; d++) {
    float kd = cr*pr - ci*pi;                       // Re(C~ w^d)
    kd += __shfl_xor(kd, 1);  kd += __shfl_xor(kd, 2);  kd += __shfl_xor(kd, 4);
    kd += __shfl_xor(kd, 8);  kd += __shfl_xor(kd, 16); kd += __shfl_xor(kd, 32);
    if (n == 0) ktap[w][d] = 2.f*kd;
    Ah[(size_t)d*192 + 64 + 2*n]   = (half_t)(2.f*qr);
    Ah[(size_t)d*192 + 64 + 2*n+1] = (half_t)(-2.f*qi);
    float npr = pr*wr - pi*wi, npi = pr*wi + pi*wr; pr = npr; pi = npi;
    float nqr = qr*wr - qi*wi, nqi = qr*wi + qi*wr; qr = nqr; qi = nqi;
  }
  wl[(h*NN+n)*2] = pr; wl[(h*NN+n)*2+1] = pi;       // w^64
  __syncthreads();
  {
    int l = n;
    half_t* row = Ah + (size_t)l*192;
    for (int m = 0; m < 64; m++)
      row[m] = (half_t)((m <= l) ? ktap[w][l - m] : 0.f);
  }
}

// ---------------- kG1: states GEMM + in-LDS scan -> SinitB f16 [h][b][c][128 n2] ----------------
__global__ __launch_bounds__(256) void kG1(const half_t* __restrict__ hT,
      const float* __restrict__ wb, const float* __restrict__ wl,
      half_t* __restrict__ SinitB) {
  __shared__ float smem[17408];                     // 69632 B: va+ub then reused as s2
  half_t* va = (half_t*)smem;                       // [128 n2][72]
  half_t* ub = va + 128*72;                         // [128 c][72]
  float*  s2 = smem;                                // [128 n2][132] (reuse after barrier)
  int t = threadIdx.x;
  int h = blockIdx.x >> 3, b = blockIdx.x & 7;
  // V build: V[2n][m]=Re(w^{63-m}), V[2n+1][m]=Im(w^{63-m})
  {
    int n = t >> 2, q4 = t & 3;
    float wr = wb[(h*NN+n)*2], wi = wb[(h*NN+n)*2+1];
    float ar = wr, ai = wi;
    #pragma unroll
    for (int i = 0; i < 4; i++) { float nr = ar*ar - ai*ai, ni = 2.f*ar*ai; ar = nr; ai = ni; } // w^16
    float pr = 1.f, pi = 0.f;
    for (int e = 0; e < 3 - q4; e++) { float nr = pr*ar - pi*ai, ni = pr*ai + pi*ar; pr = nr; pi = ni; }
    int k0 = (3 - q4)*16;
    for (int i = 0; i < 16; i++) {
      int m = 63 - (k0 + i);
      va[(2*n)*72 + m]   = (half_t)pr;
      va[(2*n+1)*72 + m] = (half_t)pi;
      float nr = pr*wr - pi*wi, ni = pr*wi + pi*wr; pr = nr; pi = ni;
    }
  }
  // U stage: ub[c][m] <- hT[b][h][c*64+m]
  {
    const half_t* src = hT + ((size_t)b*HH + h)*LL;
    #pragma unroll
    for (int i = 0; i < 4; i++) {
      int idx = t + i*256;
      int row = idx >> 3, off = (idx & 7)*8;
      *(f16x8_t*)&ub[row*72 + off] = *(const f16x8_t*)&src[row*64 + off];
    }
  }
  __syncthreads();
  int wid = t >> 6, lane = t & 63;
  int wr_ = wid >> 1, wc = wid & 1;
  int lr = lane & 15, lk = (lane >> 4)*8;
  f32x4_t acc[4][4];
  #pragma unroll
  for (int mr = 0; mr < 4; mr++)
    #pragma unroll
    for (int nc = 0; nc < 4; nc++) acc[mr][nc] = (f32x4_t){0.f,0.f,0.f,0.f};
  #pragma unroll
  for (int ks = 0; ks < 2; ks++) {
    int k = ks*32 + lk;
    f16x8_t af[4], bf[4];
    #pragma unroll
    for (int mr = 0; mr < 4; mr++) af[mr] = *(const f16x8_t*)&va[(wr_*64 + mr*16 + lr)*72 + k];
    #pragma unroll
    for (int nc = 0; nc < 4; nc++) bf[nc] = *(const f16x8_t*)&ub[(wc*64 + nc*16 + lr)*72 + k];
    #pragma unroll
    for (int mr = 0; mr < 4; mr++)
      #pragma unroll
      for (int nc = 0; nc < 4; nc++)
        acc[mr][nc] = __builtin_amdgcn_mfma_f32_16x16x32_f16(af[mr], bf[nc], acc[mr][nc], 0, 0, 0);
  }
  __syncthreads();                                  // frag reads done before s2 overwrite
  #pragma unroll
  for (int mr = 0; mr < 4; mr++)
    #pragma unroll
    for (int nc = 0; nc < 4; nc++)
      #pragma unroll
      for (int r = 0; r < 4; r++)
        s2[(wr_*64 + mr*16 + (lane>>4)*4 + r)*132 + (wc*64 + nc*16 + lr)] = acc[mr][nc][r];
  __syncthreads();
  if (t < 64) {                                     // serial scan over chunks (1 wave)
    int n = t;
    float w64r = wl[(h*NN+n)*2], w64i = wl[(h*NN+n)*2+1];
    float cr = 0.f, ci = 0.f;
    #pragma unroll 4
    for (int c = 0; c < NC; c++) {
      float lre = s2[(2*n)*132 + c], lim = s2[(2*n+1)*132 + c];
      s2[(2*n)*132 + c] = cr; s2[(2*n+1)*132 + c] = ci;
      float nr = fmaf(w64r, cr, fmaf(-w64i, ci, lre));
      float ni = fmaf(w64i, cr, fmaf(w64r, ci, lim));
      cr = nr; ci = ni;
    }
  }
  __syncthreads();
  {
    int c = t >> 1, hf = t & 1;
    half_t* dst = SinitB + (((size_t)h*BB + b)*NC + c)*128 + hf*64;
    for (int i = 0; i < 64; i += 4) {
      f16x4_t v = { (half_t)s2[(hf*64+i  )*132 + c], (half_t)s2[(hf*64+i+1)*132 + c],
                    (half_t)s2[(hf*64+i+2)*132 + c], (half_t)s2[(hf*64+i+3)*132 + c] };
      *(f16x4_t*)&dst[i] = v;
    }
  }
}

// ---------------- kG2: output GEMM  y[l][c] = [T|G][l][k] . [U;Sinit][k][c]  -> yT f16 [b][h][l] ----------------
__global__ __launch_bounds__(256) void kG2(const half_t* __restrict__ hT,
      const half_t* __restrict__ SinitB, const half_t* __restrict__ Amat,
      half_t* __restrict__ yT) {
  __shared__ half_t As[64*200];                     // 25600 B
  __shared__ half_t Bs[128*200];                    // 51200 B
  int t = threadIdx.x;
  int h = blockIdx.x >> 3, b = blockIdx.x & 7;
  const half_t* Ag = Amat + (size_t)h*64*192;
  #pragma unroll
  for (int i = 0; i < 6; i++) {
    int idx = t + i*256;                            // < 1536
    int row = idx / 24, s8 = (idx % 24)*8;
    *(f16x8_t*)&As[row*200 + s8] = *(const f16x8_t*)&Ag[(size_t)row*192 + s8];
  }
  const half_t* Ug = hT + ((size_t)b*HH + h)*LL;
  const half_t* Sg = SinitB + ((size_t)h*BB + b)*NC*128;
  #pragma unroll
  for (int i = 0; i < 12; i++) {
    int idx = t + i*256;                            // < 3072
    int row = idx / 24, seg = idx % 24;
    f16x8_t v;
    if (seg < 8) v = *(const f16x8_t*)&Ug[row*64 + seg*8];
    else         v = *(const f16x8_t*)&Sg[row*128 + (seg-8)*8];
    *(f16x8_t*)&Bs[row*200 + seg*8] = v;
  }
  __syncthreads();
  int wc = t >> 6, lane = t & 63;
  int lr = lane & 15, lk = (lane >> 4)*8;
  f32x4_t acc[4][2];
  #pragma unroll
  for (int mr = 0; mr < 4; mr++) { acc[mr][0] = (f32x4_t){0.f,0.f,0.f,0.f}; acc[mr][1] = (f32x4_t){0.f,0.f,0.f,0.f}; }
  #pragma unroll
  for (int ks = 0; ks < 6; ks++) {
    int k = ks*32 + lk;
    f16x8_t af[4], bf[2];
    #pragma unroll
    for (int mr = 0; mr < 4; mr++) af[mr] = *(const f16x8_t*)&As[(mr*16 + lr)*200 + k];
    #pragma unroll
    for (int nc = 0; nc < 2; nc++) bf[nc] = *(const f16x8_t*)&Bs[(wc*32 + nc*16 + lr)*200 + k];
    #pragma unroll
    for (int mr = 0; mr < 4; mr++)
      #pragma unroll
      for (int nc = 0; nc < 2; nc++)
        acc[mr][nc] = __builtin_amdgcn_mfma_f32_16x16x32_f16(af[mr], bf[nc], acc[mr][nc], 0, 0, 0);
  }
  half_t* yp = yT + ((size_t)b*HH + h)*LL;
  #pragma unroll
  for (int mr = 0; mr < 4; mr++)
    #pragma unroll
    for (int nc = 0; nc < 2; nc++) {
      int c  = wc*32 + nc*16 + lr;
      int l0 = mr*16 + (lane>>4)*4;
      f16x4_t v = { (half_t)acc[mr][nc][0], (half_t)acc[mr][nc][1],
                    (half_t)acc[mr][nc][2], (half_t)acc[mr][nc][3] };
      *(f16x4_t*)&yp[c*64 + l0] = v;
    }
}

// ---------------- kD: skip + gelu + MFMA GLU + residual + rmsnorm (in-place) + hT dual-write ----------------
// Stage 1 (ct,rg mapping): gelu -> ylds f16 [32][136]; u kept in regs.
// Stage 2 (wave mapping): z[32 l][256 g] = ylds[32][128] x Wf16[128][256] via mfma_f32_16x16x32_f16.
//   A-frag from ylds [M][K] row-major (pad 136: 2-way-free); B-frag from global wgt [g][h]=[N][K].
//   Wave w owns nt in {2w,2w+1,2w+8,2w+9} (a-cols and matching gate-cols).
// Stage 3-5: bias+sigmoid+residual into zlds a-cols, rmsnorm, dual write (round-8 structure).
__global__ __launch_bounds__(256) void kD(const half_t* __restrict__ yT,
     const float* __restrict__ hin, const float* __restrict__ dskip,
     const half_t* __restrict__ wgt, const float* __restrict__ bglu,
     float* __restrict__ hout, half_t* __restrict__ hT) {
  __shared__ half_t ylds[32][136];
  __shared__ float  zlds[32][264];
  __shared__ float  rnorm[32];
  size_t row0 = (size_t)blockIdx.x * 32;
  int b  = (int)(row0 >> 13);
  int l0 = (int)(row0 & 8191);
  int t = threadIdx.x;
  int ct = t & 63, rg = t >> 6;
  int h0 = 2*ct, h1 = 2*ct + 1;
  // ---- stage 1: y (2x f16x8) + u (8x float2) -> gelu f16 into ylds
  const half_t* yb = yT + ((size_t)b*HH)*LL + l0 + rg*8;
  f16x8_t y0 = *(const f16x8_t*)&yb[(size_t)h0*LL];
  f16x8_t y1 = *(const f16x8_t*)&yb[(size_t)h1*LL];
  float2 u[8];
  const float* ubase = hin + (row0 + rg*8)*HH + h0;
  #pragma unroll
  for (int i = 0; i < 8; i++) u[i] = *(const float2*)&ubase[(size_t)i*HH];
  float d0 = dskip[h0], d1 = dskip[h1];
  #pragma unroll
  for (int i = 0; i < 8; i++) {
    float vv[2] = { fmaf(u[i].x, d0, (float)y0[i]), fmaf(u[i].y, d1, (float)y1[i]) };
    float g2[2];
    #pragma unroll
    for (int q = 0; q < 2; q++) {
      float v = vv[q];
      float arg = 0.7978845608028654f*(v + 0.044715f*v*v*v);
      arg = fminf(fmaxf(arg, -15.f), 15.f);
      float e = __expf(2.f*arg);
      float th = (e - 1.f)/(e + 1.f);
      g2[q] = 0.5f*v*(1.f + th);
    }
    f16x2_t p = { (half_t)g2[0], (half_t)g2[1] };
    *(f16x2_t*)&ylds[rg*8 + i][h0] = p;
  }
  __syncthreads();
  // ---- stage 2: MFMA GLU
  {
    int w = t >> 6, lane = t & 63;
    int lr = lane & 15, lq = lane >> 4;
    f16x8_t af[2][4];
    #pragma unroll
    for (int mt = 0; mt < 2; mt++)
      #pragma unroll
      for (int ks = 0; ks < 4; ks++)
        af[mt][ks] = *(const f16x8_t*)&ylds[mt*16 + lr][ks*32 + lq*8];
    int ntl[4] = { 2*w, 2*w+1, 2*w+8, 2*w+9 };
    f32x4_t acc[2][4];
    #pragma unroll
    for (int mt = 0; mt < 2; mt++)
      #pragma unroll
      for (int p = 0; p < 4; p++) acc[mt][p] = (f32x4_t){0.f,0.f,0.f,0.f};
    #pragma unroll
    for (int p = 0; p < 4; p++) {
      int nt = ntl[p];
      #pragma unroll
      for (int ks = 0; ks < 4; ks++) {
        f16x8_t bf = *(const f16x8_t*)&wgt[(size_t)(nt*16 + lr)*HH + ks*32 + lq*8];
        #pragma unroll
        for (int mt = 0; mt < 2; mt++)
          acc[mt][p] = __builtin_amdgcn_mfma_f32_16x16x32_f16(af[mt][ks], bf, acc[mt][p], 0, 0, 0);
      }
    }
    #pragma unroll
    for (int mt = 0; mt < 2; mt++)
      #pragma unroll
      for (int p = 0; p < 4; p++)
        #pragma unroll
        for (int r = 0; r < 4; r++)
          zlds[mt*16 + lq*4 + r][ntl[p]*16 + lr] = acc[mt][p][r];
  }
  __syncthreads();
  // ---- stage 3: z = (a+ba)*sigmoid(g+bg) + u  -> back into zlds a-cols
  {
    float ba0 = bglu[h0], ba1 = bglu[h1];
    float bg0 = bglu[h0+128], bg1 = bglu[h1+128];
    #pragma unroll
    for (int r = 0; r < 8; r++) {
      int row = rg*8 + r;
      float a0 = zlds[row][h0] + ba0;
      float a1 = zlds[row][h1] + ba1;
      float g0 = zlds[row][h0+128] + bg0;
      float g1 = zlds[row][h1+128] + bg1;
      float s0 = 1.f/(1.f + __expf(-g0));
      float s1 = 1.f/(1.f + __expf(-g1));
      zlds[row][h0] = fmaf(a0, s0, u[r].x);
      zlds[row][h1] = fmaf(a1, s1, u[r].y);
    }
  }
  __syncthreads();
  // ---- stage 4: row 2-norms over cols 0..127
  #pragma unroll
  for (int i = 0; i < 4; i++) {
    int idx = i*256 + t;
    int row = idx >> 5, c4 = idx & 31;
    const float4 f = *reinterpret_cast<const float4*>(&zlds[row][c4*4]);
    float s = fmaf(f.x, f.x, fmaf(f.y, f.y, fmaf(f.z, f.z, f.w*f.w)));
    s += __shfl_xor(s, 1); s += __shfl_xor(s, 2); s += __shfl_xor(s, 4);
    s += __shfl_xor(s, 8); s += __shfl_xor(s, 16);
    if ((t & 31) == 0) rnorm[row] = s;
  }
  __syncthreads();
  // ---- stage 5: scale; wide writes to hout (float2) and hT (2x f16x8)
  f16x8_t o0, o1;
  #pragma unroll
  for (int r = 0; r < 8; r++) {
    int row = rg*8 + r;
    float scale = 11.313708498984761f / fmaxf(sqrtf(rnorm[row]), 1e-12f);
    float z0 = zlds[row][h0]*scale, z1 = zlds[row][h1]*scale;
    *reinterpret_cast<float2*>(&hout[(row0 + row)*HH + h0]) = make_float2(z0, z1);
    o0[r] = (half_t)z0;
    o1[r] = (half_t)z1;
  }
  half_t* hb = hT + (size_t)b*HH*LL + l0 + rg*8;
  *(f16x8_t*)&hb[(size_t)h0*LL] = o0;
  *(f16x8_t*)&hb[(size_t)h1*LL] = o1;
}

// ---------------- kE: out = h @ W_out + b_out ----------------
__global__ __launch_bounds__(256) void kE(const float* __restrict__ hin,
      const float4* __restrict__ wo4, const float* __restrict__ bout,
      float* __restrict__ out) {
  __shared__ float hs[64][HH];
  size_t row0 = (size_t)blockIdx.x * 64;
  int t = threadIdx.x;
  #pragma unroll
  for (int k = 0; k < 8; k++) {
    int idx = t + k*256;
    int r = idx >> 5, c4 = idx & 31;
    *reinterpret_cast<float4*>(&hs[r][c4*4]) =
        *reinterpret_cast<const float4*>(&hin[(row0 + r)*HH + c4*4]);
  }
  __syncthreads();
  int ct = t & 31, rg = t >> 5;
  float acc[8][2];
  float b0 = bout[2*ct], b1 = bout[2*ct+1];
  #pragma unroll
  for (int r = 0; r < 8; r++) { acc[r][0] = b0; acc[r][1] = b1; }
  for (int h4 = 0; h4 < 32; h4++) {
    float4 w0 = wo4[h4*64 + 2*ct];
    float4 w1 = wo4[h4*64 + 2*ct+1];
    #pragma unroll
    for (int r = 0; r < 8; r++) {
      const float4 h4v = *reinterpret_cast<const float4*>(&hs[rg*8 + r][h4*4]);
      acc[r][0] = fmaf(h4v.x, w0.x, fmaf(h4v.y, w0.y, fmaf(h4v.z, w0.z, fmaf(h4v.w, w0.w, acc[r][0]))));
      acc[r][1] = fmaf(h4v.x, w1.x, fmaf(h4v.y, w1.y, fmaf(h4v.z, w1.z, fmaf(h4v.w, w1.w, acc[r][1]))));
    }
  }
  #pragma unroll
  for (int r = 0; r < 8; r++) {
    float2 v = make_float2(acc[r][0], acc[r][1]);
    *reinterpret_cast<float2*>(&out[(row0 + rg*8 + r)*DD + 2*ct]) = v;
  }
}

extern "C" void kernel_launch(void* const* d_in, const int* in_sizes, int n_in,
                              void* d_out, int out_size, void* d_ws, size_t ws_size,
                              hipStream_t stream) {
  const float* x     = (const float*)d_in[0];
  const float* Win   = (const float*)d_in[1];
  const float* bin   = (const float*)d_in[2];
  const float* logdt = (const float*)d_in[3];
  const float* logA  = (const float*)d_in[4];
  const float* Aim   = (const float*)d_in[5];
  const float* Cre   = (const float*)d_in[6];
  const float* Cim   = (const float*)d_in[7];
  const float* Dsk   = (const float*)d_in[8];
  const float* Wglu  = (const float*)d_in[9];
  const float* bglu  = (const float*)d_in[10];
  const float* Wout  = (const float*)d_in[11];
  const float* bout  = (const float*)d_in[12];
  float* out = (float*)d_out;

  float* ws   = (float*)d_ws;
  float* wb   = ws;                         // 16384
  float* wl   = wb  + SZ_WB;                // 16384
  float* wgtF = wl  + SZ_WL;                // 49152 (f16 Wglu)
  float* wo4  = wgtF + SZ_WGT;              // 8192
  float* wi4  = wo4 + SZ_WO4;               // 8192
  float* amF  = wi4 + SZ_WI4;               // Amat f16
  float* sbF  = amF + SZ_AM;                // SinitB f16
  float* htF  = sbF + SZ_SB;                // hT f16
  float* ytF  = htF + SZ_HT;                // yT f16
  float* hA   = ytF + SZ_YT;                // fp32 stream
  // total ≈ 26.05M floats ≈ 104.2 MB
  half_t* wgt    = (half_t*)wgtF;
  half_t* Amat   = (half_t*)amF;
  half_t* SinitB = (half_t*)sbF;
  half_t* hT     = (half_t*)htF;
  half_t* yT     = (half_t*)ytF;

  kW1<<<dim3(48), dim3(256), 0, stream>>>(Wglu, wgt);
  kW2<<<dim3(8),  dim3(256), 0, stream>>>(Wout, (float4*)wo4);
  kW3<<<dim3(8),  dim3(256), 0, stream>>>(Win,  (float4*)wi4);
  kIn<<<dim3(2048), dim3(256), 0, stream>>>(x, (const float4*)wi4, bin, hA, hT);

  for (int layer = 0; layer < NLAYER; ++layer) {
    kP2<<<dim3(32),   dim3(256), 0, stream>>>(logdt, logA, Aim, Cre, Cim, layer, wb, wl, Amat);
    kG1<<<dim3(1024), dim3(256), 0, stream>>>(hT, wb, wl, SinitB);
    kG2<<<dim3(1024), dim3(256), 0, stream>>>(hT, SinitB, Amat, yT);
    kD <<<dim3(2048), dim3(256), 0, stream>>>(yT, hA, Dsk + layer*HH,
                       wgt + (size_t)layer*256*HH,
                       bglu + layer*2*HH, hA, hT);
  }
  kE<<<dim3(1024), dim3(256), 0, stream>>>(hA, (const float4*)wo4, bout, out);
}

// Round 11
// 330.306 us; speedup vs baseline: 2.1268x; 1.2384x over previous
//
#include <hip/hip_runtime.h>
#include <math.h>

#define BB 8
#define LL 8192
#define DD 64
#define HH 128
#define NN 64
#define NLAYER 3
#define LC 64          // chunk length
#define NC 128         // chunks per (b,h) sequence

typedef _Float16 half_t;
typedef _Float16 f16x8_t __attribute__((ext_vector_type(8)));
typedef _Float16 f16x4_t __attribute__((ext_vector_type(4)));
typedef _Float16 f16x2_t __attribute__((ext_vector_type(2)));
typedef float    f32x4_t __attribute__((ext_vector_type(4)));

// workspace sizes in float units
#define SZ_WB   ((size_t)HH*NN*2)            // 16384 (w complex fp32, per layer)
#define SZ_WGT  ((size_t)NLAYER*256*HH/2)    // 49152 (Wglu f16 [l][g][h])
#define SZ_WO4  ((size_t)32*64*4)            // 8192
#define SZ_WI4  ((size_t)16*128*4)           // 8192
#define SZ_AM   ((size_t)HH*64*192/2)        // 786432  (f16, per layer)
#define SZ_SB   ((size_t)HH*BB*NC*128/2)     // 8388608 (f16 [h][b][c][128 n2])
#define SZ_HT   ((size_t)BB*HH*LL/2)         // 4194304 (f16 [b][h][l])
#define SZ_YT   ((size_t)BB*HH*LL/2)         // 4194304 (f16 [b][h][l])
#define SZ_H    ((size_t)BB*LL*HH)           // 8388608 (fp32, written only by last kD)

// ---------------- weight prep ----------------
__global__ __launch_bounds__(256) void kW1(const float* __restrict__ Wglu,
                                           half_t* __restrict__ wgt) {
  int tid = blockIdx.x*256 + threadIdx.x;        // < 3*256*128/8 = 12288
  const float* src = Wglu + (size_t)tid*8;
  f16x8_t v;
  #pragma unroll
  for (int i = 0; i < 8; i++) v[i] = (half_t)src[i];
  *(f16x8_t*)&wgt[(size_t)tid*8] = v;
}
__global__ __launch_bounds__(256) void kW2(const float* __restrict__ Wout,
                                           float4* __restrict__ wo4) {
  int tid = blockIdx.x*256 + threadIdx.x;        // < 2048
  int h4 = tid >> 6, d = tid & 63;
  wo4[tid] = make_float4(Wout[(4*h4+0)*DD + d], Wout[(4*h4+1)*DD + d],
                         Wout[(4*h4+2)*DD + d], Wout[(4*h4+3)*DD + d]);
}
__global__ __launch_bounds__(256) void kW3(const float* __restrict__ Win,
                                           float4* __restrict__ wip4) {
  int tid = blockIdx.x*256 + threadIdx.x;        // < 2048
  int k4 = tid >> 7, col = tid & 127;
  wip4[tid] = make_float4(Win[(4*k4+0)*HH + col], Win[(4*k4+1)*HH + col],
                          Win[(4*k4+2)*HH + col], Win[(4*k4+3)*HH + col]);
}

// ---------------- kIn: h = x @ W_in + b_in -> f16 [b][h][l] only ----------------
__global__ __launch_bounds__(256) void kIn(const float* __restrict__ x,
      const float4* __restrict__ wip4, const float* __restrict__ bin,
      half_t* __restrict__ hT) {
  __shared__ float xs[32][DD];
  size_t row0 = (size_t)blockIdx.x * 32;
  int t = threadIdx.x;
  #pragma unroll
  for (int k = 0; k < 2; k++) {
    int idx = t + k*256;
    int r = idx >> 4, c4 = idx & 15;
    *reinterpret_cast<float4*>(&xs[r][c4*4]) =
        *reinterpret_cast<const float4*>(&x[(row0 + r)*DD + c4*4]);
  }
  __syncthreads();
  int ct = t & 63, rg = t >> 6;
  float acc[8][2];
  float b0 = bin[2*ct], b1 = bin[2*ct+1];
  #pragma unroll
  for (int r = 0; r < 8; r++) { acc[r][0] = b0; acc[r][1] = b1; }
  for (int k4 = 0; k4 < 16; k4++) {
    float4 w0 = wip4[k4*128 + 2*ct];
    float4 w1 = wip4[k4*128 + 2*ct+1];
    #pragma unroll
    for (int r = 0; r < 8; r++) {
      const float4 x4 = *reinterpret_cast<const float4*>(&xs[rg*8 + r][k4*4]);
      acc[r][0] = fmaf(x4.x, w0.x, fmaf(x4.y, w0.y, fmaf(x4.z, w0.z, fmaf(x4.w, w0.w, acc[r][0]))));
      acc[r][1] = fmaf(x4.x, w1.x, fmaf(x4.y, w1.y, fmaf(x4.z, w1.z, fmaf(x4.w, w1.w, acc[r][1]))));
    }
  }
  size_t bb = row0 >> 13;
  int l0 = (int)(row0 & 8191) + rg*8;
  f16x8_t o0, o1;
  #pragma unroll
  for (int r = 0; r < 8; r++) { o0[r] = (half_t)acc[r][0]; o1[r] = (half_t)acc[r][1]; }
  *(f16x8_t*)&hT[((size_t)bb*HH + 2*ct  )*LL + l0] = o0;
  *(f16x8_t*)&hT[((size_t)bb*HH + 2*ct+1)*LL + l0] = o1;
}

// ---------------- kP2: ALL layers' SSM params -> wb3, wl3, Amat3 (out of serial chain) ----------------
__global__ __launch_bounds__(256) void kP2(const float* __restrict__ logdt,
   const float* __restrict__ logA, const float* __restrict__ Aim,
   const float* __restrict__ Cre, const float* __restrict__ Cim,
   float* __restrict__ wb3, float* __restrict__ wl3, half_t* __restrict__ Amat3) {
  __shared__ float ktap[4][64];
  int layer = blockIdx.x >> 5;
  int blk   = blockIdx.x & 31;
  float* wb = wb3 + (size_t)layer*SZ_WB;
  float* wl = wl3 + (size_t)layer*SZ_WB;
  half_t* Amat = Amat3 + (size_t)layer*HH*64*192;
  int t = threadIdx.x;
  int w = t >> 6;                 // wave = local h
  int n = t & 63;
  int h = blk*4 + w;
  float dt = expf(logdt[layer*HH + h]);
  int idx = (layer*HH + h)*NN + n;
  float ar = -expf(logA[idx]);
  float ai = Aim[idx];
  float er = expf(dt*ar);
  float wr = er*cosf(dt*ai), wi = er*sinf(dt*ai);   // w = exp(dt*A)
  float inv = 1.f/(ar*ar + ai*ai);
  float mr = wr - 1.f, mi = wi;                     // expm1(dtA)
  float tr = (mr*ar + mi*ai)*inv;                   // expm1(dtA)/A
  float ti = (mi*ar - mr*ai)*inv;
  float c0 = Cre[idx], c1 = Cim[idx];
  float cr = c0*tr - c1*ti, ci = c0*ti + c1*tr;     // C_eff
  wb[(h*NN+n)*2] = wr; wb[(h*NN+n)*2+1] = wi;
  float pr = 1.f, pi = 0.f;                         // w^d
  float qr = cr*wr - ci*wi, qi = cr*wi + ci*wr;     // C~ w^{d+1}
  half_t* Ah = Amat + (size_t)h*64*192;
  for (int d = 0; d < 64; d++) {
    float kd = cr*pr - ci*pi;                       // Re(C~ w^d)
    kd += __shfl_xor(kd, 1);  kd += __shfl_xor(kd, 2);  kd += __shfl_xor(kd, 4);
    kd += __shfl_xor(kd, 8);  kd += __shfl_xor(kd, 16); kd += __shfl_xor(kd, 32);
    if (n == 0) ktap[w][d] = 2.f*kd;
    Ah[(size_t)d*192 + 64 + 2*n]   = (half_t)(2.f*qr);
    Ah[(size_t)d*192 + 64 + 2*n+1] = (half_t)(-2.f*qi);
    float npr = pr*wr - pi*wi, npi = pr*wi + pi*wr; pr = npr; pi = npi;
    float nqr = qr*wr - qi*wi, nqi = qr*wi + qi*wr; qr = nqr; qi = nqi;
  }
  wl[(h*NN+n)*2] = pr; wl[(h*NN+n)*2+1] = pi;       // w^64
  __syncthreads();
  {
    int l = n;
    half_t* row = Ah + (size_t)l*192;
    for (int m = 0; m < 64; m++)
      row[m] = (half_t)((m <= l) ? ktap[w][l - m] : 0.f);
  }
}

// ---------------- kG1: states GEMM + in-LDS scan -> SinitB f16 [h][b][c][128 n2] ----------------
__global__ __launch_bounds__(256) void kG1(const half_t* __restrict__ hT,
      const float* __restrict__ wb, const float* __restrict__ wl,
      half_t* __restrict__ SinitB) {
  __shared__ float smem[17408];                     // 69632 B: va+ub then reused as s2
  half_t* va = (half_t*)smem;                       // [128 n2][72]
  half_t* ub = va + 128*72;                         // [128 c][72]
  float*  s2 = smem;                                // [128 n2][132] (reuse after barrier)
  int t = threadIdx.x;
  int h = blockIdx.x >> 3, b = blockIdx.x & 7;
  // V build: V[2n][m]=Re(w^{63-m}), V[2n+1][m]=Im(w^{63-m})
  {
    int n = t >> 2, q4 = t & 3;
    float wr = wb[(h*NN+n)*2], wi = wb[(h*NN+n)*2+1];
    float ar = wr, ai = wi;
    #pragma unroll
    for (int i = 0; i < 4; i++) { float nr = ar*ar - ai*ai, ni = 2.f*ar*ai; ar = nr; ai = ni; } // w^16
    float pr = 1.f, pi = 0.f;
    for (int e = 0; e < 3 - q4; e++) { float nr = pr*ar - pi*ai, ni = pr*ai + pi*ar; pr = nr; pi = ni; }
    int k0 = (3 - q4)*16;
    for (int i = 0; i < 16; i++) {
      int m = 63 - (k0 + i);
      va[(2*n)*72 + m]   = (half_t)pr;
      va[(2*n+1)*72 + m] = (half_t)pi;
      float nr = pr*wr - pi*wi, ni = pr*wi + pi*wr; pr = nr; pi = ni;
    }
  }
  // U stage: ub[c][m] <- hT[b][h][c*64+m]
  {
    const half_t* src = hT + ((size_t)b*HH + h)*LL;
    #pragma unroll
    for (int i = 0; i < 4; i++) {
      int idx = t + i*256;
      int row = idx >> 3, off = (idx & 7)*8;
      *(f16x8_t*)&ub[row*72 + off] = *(const f16x8_t*)&src[row*64 + off];
    }
  }
  __syncthreads();
  int wid = t >> 6, lane = t & 63;
  int wr_ = wid >> 1, wc = wid & 1;
  int lr = lane & 15, lk = (lane >> 4)*8;
  f32x4_t acc[4][4];
  #pragma unroll
  for (int mr = 0; mr < 4; mr++)
    #pragma unroll
    for (int nc = 0; nc < 4; nc++) acc[mr][nc] = (f32x4_t){0.f,0.f,0.f,0.f};
  #pragma unroll
  for (int ks = 0; ks < 2; ks++) {
    int k = ks*32 + lk;
    f16x8_t af[4], bf[4];
    #pragma unroll
    for (int mr = 0; mr < 4; mr++) af[mr] = *(const f16x8_t*)&va[(wr_*64 + mr*16 + lr)*72 + k];
    #pragma unroll
    for (int nc = 0; nc < 4; nc++) bf[nc] = *(const f16x8_t*)&ub[(wc*64 + nc*16 + lr)*72 + k];
    #pragma unroll
    for (int mr = 0; mr < 4; mr++)
      #pragma unroll
      for (int nc = 0; nc < 4; nc++)
        acc[mr][nc] = __builtin_amdgcn_mfma_f32_16x16x32_f16(af[mr], bf[nc], acc[mr][nc], 0, 0, 0);
  }
  __syncthreads();                                  // frag reads done before s2 overwrite
  #pragma unroll
  for (int mr = 0; mr < 4; mr++)
    #pragma unroll
    for (int nc = 0; nc < 4; nc++)
      #pragma unroll
      for (int r = 0; r < 4; r++)
        s2[(wr_*64 + mr*16 + (lane>>4)*4 + r)*132 + (wc*64 + nc*16 + lr)] = acc[mr][nc][r];
  __syncthreads();
  if (t < 64) {                                     // serial scan over chunks (1 wave)
    int n = t;
    float w64r = wl[(h*NN+n)*2], w64i = wl[(h*NN+n)*2+1];
    float cr = 0.f, ci = 0.f;
    #pragma unroll 4
    for (int c = 0; c < NC; c++) {
      float lre = s2[(2*n)*132 + c], lim = s2[(2*n+1)*132 + c];
      s2[(2*n)*132 + c] = cr; s2[(2*n+1)*132 + c] = ci;
      float nr = fmaf(w64r, cr, fmaf(-w64i, ci, lre));
      float ni = fmaf(w64i, cr, fmaf(w64r, ci, lim));
      cr = nr; ci = ni;
    }
  }
  __syncthreads();
  {
    int c = t >> 1, hf = t & 1;
    half_t* dst = SinitB + (((size_t)h*BB + b)*NC + c)*128 + hf*64;
    for (int i = 0; i < 64; i += 4) {
      f16x4_t v = { (half_t)s2[(hf*64+i  )*132 + c], (half_t)s2[(hf*64+i+1)*132 + c],
                    (half_t)s2[(hf*64+i+2)*132 + c], (half_t)s2[(hf*64+i+3)*132 + c] };
      *(f16x4_t*)&dst[i] = v;
    }
  }
}

// ---------------- kG2: output GEMM  y[l][c] = [T|G][l][k] . [U;Sinit][k][c]  -> yT f16 [b][h][l] ----------------
__global__ __launch_bounds__(256) void kG2(const half_t* __restrict__ hT,
      const half_t* __restrict__ SinitB, const half_t* __restrict__ Amat,
      half_t* __restrict__ yT) {
  __shared__ half_t As[64*200];                     // 25600 B
  __shared__ half_t Bs[128*200];                    // 51200 B
  int t = threadIdx.x;
  int h = blockIdx.x >> 3, b = blockIdx.x & 7;
  const half_t* Ag = Amat + (size_t)h*64*192;
  #pragma unroll
  for (int i = 0; i < 6; i++) {
    int idx = t + i*256;                            // < 1536
    int row = idx / 24, s8 = (idx % 24)*8;
    *(f16x8_t*)&As[row*200 + s8] = *(const f16x8_t*)&Ag[(size_t)row*192 + s8];
  }
  const half_t* Ug = hT + ((size_t)b*HH + h)*LL;
  const half_t* Sg = SinitB + ((size_t)h*BB + b)*NC*128;
  #pragma unroll
  for (int i = 0; i < 12; i++) {
    int idx = t + i*256;                            // < 3072
    int row = idx / 24, seg = idx % 24;
    f16x8_t v;
    if (seg < 8) v = *(const f16x8_t*)&Ug[row*64 + seg*8];
    else         v = *(const f16x8_t*)&Sg[row*128 + (seg-8)*8];
    *(f16x8_t*)&Bs[row*200 + seg*8] = v;
  }
  __syncthreads();
  int wc = t >> 6, lane = t & 63;
  int lr = lane & 15, lk = (lane >> 4)*8;
  f32x4_t acc[4][2];
  #pragma unroll
  for (int mr = 0; mr < 4; mr++) { acc[mr][0] = (f32x4_t){0.f,0.f,0.f,0.f}; acc[mr][1] = (f32x4_t){0.f,0.f,0.f,0.f}; }
  #pragma unroll
  for (int ks = 0; ks < 6; ks++) {
    int k = ks*32 + lk;
    f16x8_t af[4], bf[2];
    #pragma unroll
    for (int mr = 0; mr < 4; mr++) af[mr] = *(const f16x8_t*)&As[(mr*16 + lr)*200 + k];
    #pragma unroll
    for (int nc = 0; nc < 2; nc++) bf[nc] = *(const f16x8_t*)&Bs[(wc*32 + nc*16 + lr)*200 + k];
    #pragma unroll
    for (int mr = 0; mr < 4; mr++)
      #pragma unroll
      for (int nc = 0; nc < 2; nc++)
        acc[mr][nc] = __builtin_amdgcn_mfma_f32_16x16x32_f16(af[mr], bf[nc], acc[mr][nc], 0, 0, 0);
  }
  half_t* yp = yT + ((size_t)b*HH + h)*LL;
  #pragma unroll
  for (int mr = 0; mr < 4; mr++)
    #pragma unroll
    for (int nc = 0; nc < 2; nc++) {
      int c  = wc*32 + nc*16 + lr;
      int l0 = mr*16 + (lane>>4)*4;
      f16x4_t v = { (half_t)acc[mr][nc][0], (half_t)acc[mr][nc][1],
                    (half_t)acc[mr][nc][2], (half_t)acc[mr][nc][3] };
      *(f16x4_t*)&yp[c*64 + l0] = v;
    }
}

// ---------------- kD: skip+gelu+MFMA GLU(in-reg gate)+residual+rmsnorm, f16 stream in/out ----------------
// u read from hT f16; hout fp32 written only when last!=0 (for kE).
__global__ __launch_bounds__(256) void kD(const half_t* __restrict__ yT,
     const half_t* __restrict__ hTin, const float* __restrict__ dskip,
     const half_t* __restrict__ wgt, const float* __restrict__ bglu,
     half_t* __restrict__ hT, float* __restrict__ hout, int last) {
  __shared__ half_t ylds[32][136];
  __shared__ float  zlds[32][133];
  __shared__ float  rnorm[32];
  size_t row0 = (size_t)blockIdx.x * 32;
  int b  = (int)(row0 >> 13);
  int l0 = (int)(row0 & 8191);
  int t = threadIdx.x;
  int ct = t & 63, rg = t >> 6;
  int h0 = 2*ct, h1 = 2*ct + 1;
  // ---- stage 1: y + u (both f16 [b][h][l], 16B loads); gelu -> ylds; u kept in regs
  const half_t* yb = yT  + ((size_t)b*HH)*LL + l0 + rg*8;
  const half_t* ub = hTin + ((size_t)b*HH)*LL + l0 + rg*8;
  f16x8_t y0 = *(const f16x8_t*)&yb[(size_t)h0*LL];
  f16x8_t y1 = *(const f16x8_t*)&yb[(size_t)h1*LL];
  f16x8_t u0 = *(const f16x8_t*)&ub[(size_t)h0*LL];
  f16x8_t u1 = *(const f16x8_t*)&ub[(size_t)h1*LL];
  float d0 = dskip[h0], d1 = dskip[h1];
  #pragma unroll
  for (int i = 0; i < 8; i++) {
    float vv[2] = { fmaf((float)u0[i], d0, (float)y0[i]),
                    fmaf((float)u1[i], d1, (float)y1[i]) };
    float g2[2];
    #pragma unroll
    for (int q = 0; q < 2; q++) {
      float v = vv[q];
      float arg = 0.7978845608028654f*(v + 0.044715f*v*v*v);
      arg = fminf(fmaxf(arg, -15.f), 15.f);
      float e = __expf(2.f*arg);
      float th = (e - 1.f)/(e + 1.f);
      g2[q] = 0.5f*v*(1.f + th);
    }
    f16x2_t p = { (half_t)g2[0], (half_t)g2[1] };
    *(f16x2_t*)&ylds[rg*8 + i][h0] = p;
  }
  __syncthreads();
  // ---- stage 2: MFMA GLU with in-register gate
  {
    int w = t >> 6, lane = t & 63;
    int lr = lane & 15, lq = lane >> 4;
    f16x8_t af[2][4];
    #pragma unroll
    for (int mt = 0; mt < 2; mt++)
      #pragma unroll
      for (int ks = 0; ks < 4; ks++)
        af[mt][ks] = *(const f16x8_t*)&ylds[mt*16 + lr][ks*32 + lq*8];
    int ntl[4] = { 2*w, 2*w+1, 2*w+8, 2*w+9 };     // p=0,1 a-tiles; p=2,3 matching gate-tiles
    f32x4_t acc[2][4];
    #pragma unroll
    for (int mt = 0; mt < 2; mt++)
      #pragma unroll
      for (int p = 0; p < 4; p++) acc[mt][p] = (f32x4_t){0.f,0.f,0.f,0.f};
    #pragma unroll
    for (int p = 0; p < 4; p++) {
      int nt = ntl[p];
      #pragma unroll
      for (int ks = 0; ks < 4; ks++) {
        f16x8_t bf = *(const f16x8_t*)&wgt[(size_t)(nt*16 + lr)*HH + ks*32 + lq*8];
        #pragma unroll
        for (int mt = 0; mt < 2; mt++)
          acc[mt][p] = __builtin_amdgcn_mfma_f32_16x16x32_f16(af[mt][ks], bf, acc[mt][p], 0, 0, 0);
      }
    }
    // in-reg GLU: col(p) = 32w + p*16 + lr; gate col = col + 128
    #pragma unroll
    for (int p = 0; p < 2; p++) {
      int col = 32*w + p*16 + lr;
      float ba = bglu[col], bg = bglu[col + 128];
      #pragma unroll
      for (int mt = 0; mt < 2; mt++)
        #pragma unroll
        for (int r = 0; r < 4; r++) {
          float a = acc[mt][p][r]   + ba;
          float g = acc[mt][p+2][r] + bg;
          float s = 1.f/(1.f + __expf(-g));
          zlds[mt*16 + lq*4 + r][col] = a*s;
        }
    }
  }
  __syncthreads();
  // ---- stage 3: + residual u -> zlds
  #pragma unroll
  for (int r = 0; r < 8; r++) {
    int row = rg*8 + r;
    zlds[row][h0] += (float)u0[r];
    zlds[row][h1] += (float)u1[r];
  }
  __syncthreads();
  // ---- stage 4: row 2-norms
  #pragma unroll
  for (int i = 0; i < 4; i++) {
    int idx = i*256 + t;
    int row = idx >> 5, c4 = idx & 31;
    const float4 f = *reinterpret_cast<const float4*>(&zlds[row][c4*4]);
    float s = fmaf(f.x, f.x, fmaf(f.y, f.y, fmaf(f.z, f.z, f.w*f.w)));
    s += __shfl_xor(s, 1); s += __shfl_xor(s, 2); s += __shfl_xor(s, 4);
    s += __shfl_xor(s, 8); s += __shfl_xor(s, 16);
    if ((t & 31) == 0) rnorm[row] = s;
  }
  __syncthreads();
  // ---- stage 5: scale; f16 stream write (+ fp32 only on last layer)
  f16x8_t o0, o1;
  #pragma unroll
  for (int r = 0; r < 8; r++) {
    int row = rg*8 + r;
    float scale = 11.313708498984761f / fmaxf(sqrtf(rnorm[row]), 1e-12f);
    float z0 = zlds[row][h0]*scale, z1 = zlds[row][h1]*scale;
    o0[r] = (half_t)z0;
    o1[r] = (half_t)z1;
    if (last) *reinterpret_cast<float2*>(&hout[(row0 + row)*HH + h0]) = make_float2(z0, z1);
  }
  half_t* hb = hT + (size_t)b*HH*LL + l0 + rg*8;
  *(f16x8_t*)&hb[(size_t)h0*LL] = o0;
  *(f16x8_t*)&hb[(size_t)h1*LL] = o1;
}

// ---------------- kE: out = h @ W_out + b_out ----------------
__global__ __launch_bounds__(256) void kE(const float* __restrict__ hin,
      const float4* __restrict__ wo4, const float* __restrict__ bout,
      float* __restrict__ out) {
  __shared__ float hs[64][HH];
  size_t row0 = (size_t)blockIdx.x * 64;
  int t = threadIdx.x;
  #pragma unroll
  for (int k = 0; k < 8; k++) {
    int idx = t + k*256;
    int r = idx >> 5, c4 = idx & 31;
    *reinterpret_cast<float4*>(&hs[r][c4*4]) =
        *reinterpret_cast<const float4*>(&hin[(row0 + r)*HH + c4*4]);
  }
  __syncthreads();
  int ct = t & 31, rg = t >> 5;
  float acc[8][2];
  float b0 = bout[2*ct], b1 = bout[2*ct+1];
  #pragma unroll
  for (int r = 0; r < 8; r++) { acc[r][0] = b0; acc[r][1] = b1; }
  for (int h4 = 0; h4 < 32; h4++) {
    float4 w0 = wo4[h4*64 + 2*ct];
    float4 w1 = wo4[h4*64 + 2*ct+1];
    #pragma unroll
    for (int r = 0; r < 8; r++) {
      const float4 h4v = *reinterpret_cast<const float4*>(&hs[rg*8 + r][h4*4]);
      acc[r][0] = fmaf(h4v.x, w0.x, fmaf(h4v.y, w0.y, fmaf(h4v.z, w0.z, fmaf(h4v.w, w0.w, acc[r][0]))));
      acc[r][1] = fmaf(h4v.x, w1.x, fmaf(h4v.y, w1.y, fmaf(h4v.z, w1.z, fmaf(h4v.w, w1.w, acc[r][1]))));
    }
  }
  #pragma unroll
  for (int r = 0; r < 8; r++) {
    float2 v = make_float2(acc[r][0], acc[r][1]);
    *reinterpret_cast<float2*>(&out[(row0 + rg*8 + r)*DD + 2*ct]) = v;
  }
}

extern "C" void kernel_launch(void* const* d_in, const int* in_sizes, int n_in,
                              void* d_out, int out_size, void* d_ws, size_t ws_size,
                              hipStream_t stream) {
  const float* x     = (const float*)d_in[0];
  const float* Win   = (const float*)d_in[1];
  const float* bin   = (const float*)d_in[2];
  const float* logdt = (const float*)d_in[3];
  const float* logA  = (const float*)d_in[4];
  const float* Aim   = (const float*)d_in[5];
  const float* Cre   = (const float*)d_in[6];
  const float* Cim   = (const float*)d_in[7];
  const float* Dsk   = (const float*)d_in[8];
  const float* Wglu  = (const float*)d_in[9];
  const float* bglu  = (const float*)d_in[10];
  const float* Wout  = (const float*)d_in[11];
  const float* bout  = (const float*)d_in[12];
  float* out = (float*)d_out;

  // Layout (round-10 failure was ws overflow at 110.8MB; ws_size evidence: 104.4MB fits,
  // 110.8 doesn't -> assume 100MiB). Amat3 is ALIASED into hA: kP2 writes it at call start,
  // last reader is kG2(L2); kD(L2,last=1) overwrites the region with hA AFTER that; kE reads hA.
  // Every replay rewrites Amat3 (kP2) and hA (kD last) before their reads. Total = 101.3 MB.
  float* ws   = (float*)d_ws;
  float* wb3  = ws;                          // 3*16384
  float* wl3  = wb3 + 3*SZ_WB;               // 3*16384
  float* wgtF = wl3 + 3*SZ_WB;               // 49152 (f16 Wglu)
  float* wo4  = wgtF + SZ_WGT;               // 8192
  float* wi4  = wo4 + SZ_WO4;                // 8192
  float* sbF  = wi4 + SZ_WI4;                // SinitB f16 (33.55MB)
  float* htF  = sbF + SZ_SB;                 // hT f16 (16.78MB)
  float* ytF  = htF + SZ_HT;                 // yT f16 (16.78MB)
  float* hA   = ytF + SZ_YT;                 // fp32 stream (33.55MB, last layer only)
  float* amF  = hA;                          // Amat3 f16 aliased into hA's first 9.44MB
  half_t* wgt    = (half_t*)wgtF;
  half_t* Amat3  = (half_t*)amF;
  half_t* SinitB = (half_t*)sbF;
  half_t* hT     = (half_t*)htF;
  half_t* yT     = (half_t*)ytF;

  kW1<<<dim3(48), dim3(256), 0, stream>>>(Wglu, wgt);
  kW2<<<dim3(8),  dim3(256), 0, stream>>>(Wout, (float4*)wo4);
  kW3<<<dim3(8),  dim3(256), 0, stream>>>(Win,  (float4*)wi4);
  kP2<<<dim3(96), dim3(256), 0, stream>>>(logdt, logA, Aim, Cre, Cim, wb3, wl3, Amat3);
  kIn<<<dim3(2048), dim3(256), 0, stream>>>(x, (const float4*)wi4, bin, hT);

  for (int layer = 0; layer < NLAYER; ++layer) {
    const float* wb = wb3 + (size_t)layer*SZ_WB;
    const float* wl = wl3 + (size_t)layer*SZ_WB;
    const half_t* Amat = Amat3 + (size_t)layer*HH*64*192;
    kG1<<<dim3(1024), dim3(256), 0, stream>>>(hT, wb, wl, SinitB);
    kG2<<<dim3(1024), dim3(256), 0, stream>>>(hT, SinitB, Amat, yT);
    kD <<<dim3(2048), dim3(256), 0, stream>>>(yT, hT, Dsk + layer*HH,
                       wgt + (size_t)layer*256*HH,
                       bglu + layer*2*HH, hT, hA, (layer == NLAYER-1) ? 1 : 0);
  }
  kE<<<dim3(1024), dim3(256), 0, stream>>>(hA, (const float4*)wo4, bout, out);
}

// Round 12
// 306.515 us; speedup vs baseline: 2.2919x; 1.0776x over previous
//
#include <hip/hip_runtime.h>
#include <math.h>

#define BB 8
#define LL 8192
#define DD 64
#define HH 128
#define NN 64
#define NLAYER 3
#define LC 64          // chunk length
#define NC 128         // chunks per (b,h) sequence
#define S2S 133        // s2 f32 row stride (pad: scan-read 4-way max)
#define SIS 136        // sinit16 row stride (halves)

typedef _Float16 half_t;
typedef _Float16 f16x8_t __attribute__((ext_vector_type(8)));
typedef _Float16 f16x4_t __attribute__((ext_vector_type(4)));
typedef _Float16 f16x2_t __attribute__((ext_vector_type(2)));
typedef float    f32x4_t __attribute__((ext_vector_type(4)));

// workspace sizes in float units
#define SZ_WB   ((size_t)HH*NN*2)            // 16384 (per layer)
#define SZ_WGT  ((size_t)NLAYER*256*HH/2)    // 49152 (Wglu f16 [l][g][h])
#define SZ_WO4  ((size_t)32*64*4)            // 8192
#define SZ_WI4  ((size_t)16*128*4)           // 8192
#define SZ_AM   ((size_t)HH*64*192/2)        // 786432  (f16, per layer)
#define SZ_HT   ((size_t)BB*HH*LL/2)         // 4194304 (f16 [b][h][l])
#define SZ_YT   ((size_t)BB*HH*LL/2)         // 4194304 (f16 [b][h][l])
#define SZ_H    ((size_t)BB*LL*HH)           // 8388608 (fp32, last kD only)

// ---------------- weight prep ----------------
__global__ __launch_bounds__(256) void kW1(const float* __restrict__ Wglu,
                                           half_t* __restrict__ wgt) {
  int tid = blockIdx.x*256 + threadIdx.x;        // < 3*256*128/8 = 12288
  const float* src = Wglu + (size_t)tid*8;
  f16x8_t v;
  #pragma unroll
  for (int i = 0; i < 8; i++) v[i] = (half_t)src[i];
  *(f16x8_t*)&wgt[(size_t)tid*8] = v;
}
__global__ __launch_bounds__(256) void kW2(const float* __restrict__ Wout,
                                           float4* __restrict__ wo4) {
  int tid = blockIdx.x*256 + threadIdx.x;        // < 2048
  int h4 = tid >> 6, d = tid & 63;
  wo4[tid] = make_float4(Wout[(4*h4+0)*DD + d], Wout[(4*h4+1)*DD + d],
                         Wout[(4*h4+2)*DD + d], Wout[(4*h4+3)*DD + d]);
}
__global__ __launch_bounds__(256) void kW3(const float* __restrict__ Win,
                                           float4* __restrict__ wip4) {
  int tid = blockIdx.x*256 + threadIdx.x;        // < 2048
  int k4 = tid >> 7, col = tid & 127;
  wip4[tid] = make_float4(Win[(4*k4+0)*HH + col], Win[(4*k4+1)*HH + col],
                          Win[(4*k4+2)*HH + col], Win[(4*k4+3)*HH + col]);
}

// ---------------- kIn: h = x @ W_in + b_in -> f16 [b][h][l] ----------------
__global__ __launch_bounds__(256) void kIn(const float* __restrict__ x,
      const float4* __restrict__ wip4, const float* __restrict__ bin,
      half_t* __restrict__ hT) {
  __shared__ float xs[32][DD];
  size_t row0 = (size_t)blockIdx.x * 32;
  int t = threadIdx.x;
  #pragma unroll
  for (int k = 0; k < 2; k++) {
    int idx = t + k*256;
    int r = idx >> 4, c4 = idx & 15;
    *reinterpret_cast<float4*>(&xs[r][c4*4]) =
        *reinterpret_cast<const float4*>(&x[(row0 + r)*DD + c4*4]);
  }
  __syncthreads();
  int ct = t & 63, rg = t >> 6;
  float acc[8][2];
  float b0 = bin[2*ct], b1 = bin[2*ct+1];
  #pragma unroll
  for (int r = 0; r < 8; r++) { acc[r][0] = b0; acc[r][1] = b1; }
  for (int k4 = 0; k4 < 16; k4++) {
    float4 w0 = wip4[k4*128 + 2*ct];
    float4 w1 = wip4[k4*128 + 2*ct+1];
    #pragma unroll
    for (int r = 0; r < 8; r++) {
      const float4 x4 = *reinterpret_cast<const float4*>(&xs[rg*8 + r][k4*4]);
      acc[r][0] = fmaf(x4.x, w0.x, fmaf(x4.y, w0.y, fmaf(x4.z, w0.z, fmaf(x4.w, w0.w, acc[r][0]))));
      acc[r][1] = fmaf(x4.x, w1.x, fmaf(x4.y, w1.y, fmaf(x4.z, w1.z, fmaf(x4.w, w1.w, acc[r][1]))));
    }
  }
  size_t bb = row0 >> 13;
  int l0 = (int)(row0 & 8191) + rg*8;
  f16x8_t o0, o1;
  #pragma unroll
  for (int r = 0; r < 8; r++) { o0[r] = (half_t)acc[r][0]; o1[r] = (half_t)acc[r][1]; }
  *(f16x8_t*)&hT[((size_t)bb*HH + 2*ct  )*LL + l0] = o0;
  *(f16x8_t*)&hT[((size_t)bb*HH + 2*ct+1)*LL + l0] = o1;
}

// ---------------- kP2: ALL layers' SSM params -> wb3, wl3, Amat3 ----------------
__global__ __launch_bounds__(256) void kP2(const float* __restrict__ logdt,
   const float* __restrict__ logA, const float* __restrict__ Aim,
   const float* __restrict__ Cre, const float* __restrict__ Cim,
   float* __restrict__ wb3, float* __restrict__ wl3, half_t* __restrict__ Amat3) {
  __shared__ float ktap[4][64];
  int layer = blockIdx.x >> 5;
  int blk   = blockIdx.x & 31;
  float* wb = wb3 + (size_t)layer*SZ_WB;
  float* wl = wl3 + (size_t)layer*SZ_WB;
  half_t* Amat = Amat3 + (size_t)layer*HH*64*192;
  int t = threadIdx.x;
  int w = t >> 6;
  int n = t & 63;
  int h = blk*4 + w;
  float dt = expf(logdt[layer*HH + h]);
  int idx = (layer*HH + h)*NN + n;
  float ar = -expf(logA[idx]);
  float ai = Aim[idx];
  float er = expf(dt*ar);
  float wr = er*cosf(dt*ai), wi = er*sinf(dt*ai);   // w = exp(dt*A)
  float inv = 1.f/(ar*ar + ai*ai);
  float mr = wr - 1.f, mi = wi;                     // expm1(dtA)
  float tr = (mr*ar + mi*ai)*inv;                   // expm1(dtA)/A
  float ti = (mi*ar - mr*ai)*inv;
  float c0 = Cre[idx], c1 = Cim[idx];
  float cr = c0*tr - c1*ti, ci = c0*ti + c1*tr;     // C_eff
  wb[(h*NN+n)*2] = wr; wb[(h*NN+n)*2+1] = wi;
  float pr = 1.f, pi = 0.f;                         // w^d
  float qr = cr*wr - ci*wi, qi = cr*wi + ci*wr;     // C~ w^{d+1}
  half_t* Ah = Amat + (size_t)h*64*192;
  for (int d = 0; d < 64; d++) {
    float kd = cr*pr - ci*pi;                       // Re(C~ w^d)
    kd += __shfl_xor(kd, 1);  kd += __shfl_xor(kd, 2);  kd += __shfl_xor(kd, 4);
    kd += __shfl_xor(kd, 8);  kd += __shfl_xor(kd, 16); kd += __shfl_xor(kd, 32);
    if (n == 0) ktap[w][d] = 2.f*kd;
    Ah[(size_t)d*192 + 64 + 2*n]   = (half_t)(2.f*qr);
    Ah[(size_t)d*192 + 64 + 2*n+1] = (half_t)(-2.f*qi);
    float npr = pr*wr - pi*wi, npi = pr*wi + pi*wr; pr = npr; pi = npi;
    float nqr = qr*wr - qi*wi, nqi = qr*wi + qi*wr; qr = nqr; qi = nqi;
  }
  wl[(h*NN+n)*2] = pr; wl[(h*NN+n)*2+1] = pi;       // w^64
  __syncthreads();
  {
    int l = n;
    half_t* row = Ah + (size_t)l*192;
    for (int m = 0; m < 64; m++)
      row[m] = (half_t)((m <= l) ? ktap[w][l - m] : 0.f);
  }
}

// ---------------- kG: FUSED states GEMM + 2-level scan + output GEMM ----------------
// Block = (h,b). Eliminates the SinitB global round-trip (67MB/layer) and the hT re-read.
// Phase 1: S_local[n2][c] = V·U^T (MFMA, f32 into s2).  Phase 2: 2-level scan over c
// (4 segs x 32 + w64^32 glue; f32 precision identical to split version), prefix states
// rounded once to f16 into sinit16[c][n2].  Phase 3: y = [T|G]·[U;Sinit], A from global
// Amat (L2-resident), B from retained ub + sinit16.
__global__ __launch_bounds__(256) void kG(const half_t* __restrict__ hT,
      const float* __restrict__ wb, const float* __restrict__ wl,
      const half_t* __restrict__ Amat, half_t* __restrict__ yT) {
  __shared__ half_t va[128*72];          // 18432 B  V matrix [n2][m]
  __shared__ half_t ub[128*72];          // 18432 B  U [c][m] (persistent)
  __shared__ float  s2[128*S2S];         // 68096 B  local sums / local prefixes [n2][c]
  __shared__ half_t sinit16[128*SIS];    // 34816 B  Sinit f16 [c][n2]
  __shared__ float  segT[4*128];         //  2048 B  segment end-states
  int t = threadIdx.x;
  int h = blockIdx.x >> 3, b = blockIdx.x & 7;
  // ---- phase 0: V build (verified kG1 code) + U stage
  {
    int n = t >> 2, q4 = t & 3;
    float wr = wb[(h*NN+n)*2], wi = wb[(h*NN+n)*2+1];
    float ar = wr, ai = wi;
    #pragma unroll
    for (int i = 0; i < 4; i++) { float nr = ar*ar - ai*ai, ni = 2.f*ar*ai; ar = nr; ai = ni; } // w^16
    float pr = 1.f, pi = 0.f;
    for (int e = 0; e < 3 - q4; e++) { float nr = pr*ar - pi*ai, ni = pr*ai + pi*ar; pr = nr; pi = ni; }
    int k0 = (3 - q4)*16;
    for (int i = 0; i < 16; i++) {
      int m = 63 - (k0 + i);
      va[(2*n)*72 + m]   = (half_t)pr;
      va[(2*n+1)*72 + m] = (half_t)pi;
      float nr = pr*wr - pi*wi, ni = pr*wi + pi*wr; pr = nr; pi = ni;
    }
  }
  {
    const half_t* src = hT + ((size_t)b*HH + h)*LL;
    #pragma unroll
    for (int i = 0; i < 4; i++) {
      int idx = t + i*256;
      int row = idx >> 3, off = (idx & 7)*8;
      *(f16x8_t*)&ub[row*72 + off] = *(const f16x8_t*)&src[row*64 + off];
    }
  }
  __syncthreads();
  int wid = t >> 6, lane = t & 63;
  int lr = lane & 15, lq = lane >> 4, lk = lq*8;
  // ---- phase 1: local-states GEMM (verified kG1 fragments)
  {
    int wr_ = wid >> 1, wc = wid & 1;
    f32x4_t acc[4][4];
    #pragma unroll
    for (int mr = 0; mr < 4; mr++)
      #pragma unroll
      for (int nc = 0; nc < 4; nc++) acc[mr][nc] = (f32x4_t){0.f,0.f,0.f,0.f};
    #pragma unroll
    for (int ks = 0; ks < 2; ks++) {
      int k = ks*32 + lk;
      f16x8_t af[4], bf[4];
      #pragma unroll
      for (int mr = 0; mr < 4; mr++) af[mr] = *(const f16x8_t*)&va[(wr_*64 + mr*16 + lr)*72 + k];
      #pragma unroll
      for (int nc = 0; nc < 4; nc++) bf[nc] = *(const f16x8_t*)&ub[(wc*64 + nc*16 + lr)*72 + k];
      #pragma unroll
      for (int mr = 0; mr < 4; mr++)
        #pragma unroll
        for (int nc = 0; nc < 4; nc++)
          acc[mr][nc] = __builtin_amdgcn_mfma_f32_16x16x32_f16(af[mr], bf[nc], acc[mr][nc], 0, 0, 0);
    }
    // s2 is disjoint from va/ub: store without an extra barrier
    #pragma unroll
    for (int mr = 0; mr < 4; mr++)
      #pragma unroll
      for (int nc = 0; nc < 4; nc++)
        #pragma unroll
        for (int r = 0; r < 4; r++)
          s2[(wr_*64 + mr*16 + lq*4 + r)*S2S + (wc*64 + nc*16 + lr)] = acc[mr][nc][r];
  }
  __syncthreads();
  // ---- phase 2: 2-level scan (all 256 threads: n = t&63, seg = t>>6)
  {
    int n = t & 63, seg = t >> 6;
    int c0 = seg*32;
    float w64r = wl[(h*NN+n)*2], w64i = wl[(h*NN+n)*2+1];
    float* pre = &s2[(2*n)*S2S];
    float* pim = &s2[(2*n+1)*S2S];
    float cr = 0.f, ci = 0.f;
    #pragma unroll 4
    for (int i = 0; i < 32; i++) {        // pass 1: local exclusive prefixes
      int c = c0 + i;
      float lre = pre[c], lim = pim[c];
      pre[c] = cr; pim[c] = ci;
      float nr = fmaf(w64r, cr, fmaf(-w64i, ci, lre));
      float ni = fmaf(w64i, cr, fmaf(w64r, ci, lim));
      cr = nr; ci = ni;
    }
    segT[seg*128 + 2*n] = cr; segT[seg*128 + 2*n+1] = ci;
    __syncthreads();
    float ar = w64r, ai = w64i;           // w64^32
    #pragma unroll
    for (int i = 0; i < 5; i++) { float nr = ar*ar - ai*ai, ni = 2.f*ar*ai; ar = nr; ai = ni; }
    float br = 0.f, bi = 0.f;             // segment base = scan of segT
    for (int k = 0; k < seg; k++) {
      float tr_ = segT[k*128 + 2*n], ti_ = segT[k*128 + 2*n+1];
      float nr = fmaf(ar, br, fmaf(-ai, bi, tr_));
      float ni = fmaf(ai, br, fmaf(ar, bi, ti_));
      br = nr; bi = ni;
    }
    float wpr = 1.f, wpi = 0.f;           // pass 2: S_c = P_c + w64^{c-c0} * base
    #pragma unroll 4
    for (int i = 0; i < 32; i++) {
      int c = c0 + i;
      float sr = pre[c] + wpr*br - wpi*bi;
      float si = pim[c] + wpr*bi + wpi*br;
      f16x2_t v = { (half_t)sr, (half_t)si };
      *(f16x2_t*)&sinit16[c*SIS + 2*n] = v;
      float nr = wpr*w64r - wpi*w64i, ni = wpr*w64i + wpi*w64r;
      wpr = nr; wpi = ni;
    }
  }
  __syncthreads();
  // ---- phase 3: output GEMM (verified kG2 fragments; A direct from global)
  {
    const half_t* Ag = Amat + (size_t)h*64*192;
    f32x4_t acc[4][2];
    #pragma unroll
    for (int mr = 0; mr < 4; mr++) { acc[mr][0] = (f32x4_t){0.f,0.f,0.f,0.f}; acc[mr][1] = (f32x4_t){0.f,0.f,0.f,0.f}; }
    #pragma unroll
    for (int ks = 0; ks < 6; ks++) {
      int k = ks*32 + lk;
      f16x8_t af[4], bf[2];
      #pragma unroll
      for (int mr = 0; mr < 4; mr++) af[mr] = *(const f16x8_t*)&Ag[(size_t)(mr*16 + lr)*192 + k];
      #pragma unroll
      for (int nc = 0; nc < 2; nc++) {
        int c = wid*32 + nc*16 + lr;
        bf[nc] = (ks < 2) ? *(const f16x8_t*)&ub[c*72 + k]
                          : *(const f16x8_t*)&sinit16[c*SIS + (k - 64)];
      }
      #pragma unroll
      for (int mr = 0; mr < 4; mr++)
        #pragma unroll
        for (int nc = 0; nc < 2; nc++)
          acc[mr][nc] = __builtin_amdgcn_mfma_f32_16x16x32_f16(af[mr], bf[nc], acc[mr][nc], 0, 0, 0);
    }
    half_t* yp = yT + ((size_t)b*HH + h)*LL;
    #pragma unroll
    for (int mr = 0; mr < 4; mr++)
      #pragma unroll
      for (int nc = 0; nc < 2; nc++) {
        int c  = wid*32 + nc*16 + lr;
        int l0 = mr*16 + lq*4;
        f16x4_t v = { (half_t)acc[mr][nc][0], (half_t)acc[mr][nc][1],
                      (half_t)acc[mr][nc][2], (half_t)acc[mr][nc][3] };
        *(f16x4_t*)&yp[c*64 + l0] = v;
      }
  }
}

// ---------------- kD: skip+gelu+MFMA GLU(in-reg gate)+residual+rmsnorm ----------------
__global__ __launch_bounds__(256) void kD(const half_t* __restrict__ yT,
     const half_t* __restrict__ hTin, const float* __restrict__ dskip,
     const half_t* __restrict__ wgt, const float* __restrict__ bglu,
     half_t* __restrict__ hT, float* __restrict__ hout, int last) {
  __shared__ half_t ylds[32][136];
  __shared__ float  zlds[32][133];
  __shared__ float  rnorm[32];
  size_t row0 = (size_t)blockIdx.x * 32;
  int b  = (int)(row0 >> 13);
  int l0 = (int)(row0 & 8191);
  int t = threadIdx.x;
  int ct = t & 63, rg = t >> 6;
  int h0 = 2*ct, h1 = 2*ct + 1;
  const half_t* yb = yT  + ((size_t)b*HH)*LL + l0 + rg*8;
  const half_t* ub = hTin + ((size_t)b*HH)*LL + l0 + rg*8;
  f16x8_t y0 = *(const f16x8_t*)&yb[(size_t)h0*LL];
  f16x8_t y1 = *(const f16x8_t*)&yb[(size_t)h1*LL];
  f16x8_t u0 = *(const f16x8_t*)&ub[(size_t)h0*LL];
  f16x8_t u1 = *(const f16x8_t*)&ub[(size_t)h1*LL];
  float d0 = dskip[h0], d1 = dskip[h1];
  #pragma unroll
  for (int i = 0; i < 8; i++) {
    float vv[2] = { fmaf((float)u0[i], d0, (float)y0[i]),
                    fmaf((float)u1[i], d1, (float)y1[i]) };
    float g2[2];
    #pragma unroll
    for (int q = 0; q < 2; q++) {
      float v = vv[q];
      float arg = 0.7978845608028654f*(v + 0.044715f*v*v*v);
      arg = fminf(fmaxf(arg, -15.f), 15.f);
      float e = __expf(2.f*arg);
      float th = (e - 1.f)/(e + 1.f);
      g2[q] = 0.5f*v*(1.f + th);
    }
    f16x2_t p = { (half_t)g2[0], (half_t)g2[1] };
    *(f16x2_t*)&ylds[rg*8 + i][h0] = p;
  }
  __syncthreads();
  {
    int w = t >> 6, lane = t & 63;
    int lr = lane & 15, lq = lane >> 4;
    f16x8_t af[2][4];
    #pragma unroll
    for (int mt = 0; mt < 2; mt++)
      #pragma unroll
      for (int ks = 0; ks < 4; ks++)
        af[mt][ks] = *(const f16x8_t*)&ylds[mt*16 + lr][ks*32 + lq*8];
    int ntl[4] = { 2*w, 2*w+1, 2*w+8, 2*w+9 };
    f32x4_t acc[2][4];
    #pragma unroll
    for (int mt = 0; mt < 2; mt++)
      #pragma unroll
      for (int p = 0; p < 4; p++) acc[mt][p] = (f32x4_t){0.f,0.f,0.f,0.f};
    #pragma unroll
    for (int p = 0; p < 4; p++) {
      int nt = ntl[p];
      #pragma unroll
      for (int ks = 0; ks < 4; ks++) {
        f16x8_t bf = *(const f16x8_t*)&wgt[(size_t)(nt*16 + lr)*HH + ks*32 + lq*8];
        #pragma unroll
        for (int mt = 0; mt < 2; mt++)
          acc[mt][p] = __builtin_amdgcn_mfma_f32_16x16x32_f16(af[mt][ks], bf, acc[mt][p], 0, 0, 0);
      }
    }
    #pragma unroll
    for (int p = 0; p < 2; p++) {
      int col = 32*w + p*16 + lr;
      float ba = bglu[col], bg = bglu[col + 128];
      #pragma unroll
      for (int mt = 0; mt < 2; mt++)
        #pragma unroll
        for (int r = 0; r < 4; r++) {
          float a = acc[mt][p][r]   + ba;
          float g = acc[mt][p+2][r] + bg;
          float s = 1.f/(1.f + __expf(-g));
          zlds[mt*16 + lq*4 + r][col] = a*s;
        }
    }
  }
  __syncthreads();
  #pragma unroll
  for (int r = 0; r < 8; r++) {
    int row = rg*8 + r;
    zlds[row][h0] += (float)u0[r];
    zlds[row][h1] += (float)u1[r];
  }
  __syncthreads();
  #pragma unroll
  for (int i = 0; i < 4; i++) {
    int idx = i*256 + t;
    int row = idx >> 5, c4 = idx & 31;
    const float4 f = *reinterpret_cast<const float4*>(&zlds[row][c4*4]);
    float s = fmaf(f.x, f.x, fmaf(f.y, f.y, fmaf(f.z, f.z, f.w*f.w)));
    s += __shfl_xor(s, 1); s += __shfl_xor(s, 2); s += __shfl_xor(s, 4);
    s += __shfl_xor(s, 8); s += __shfl_xor(s, 16);
    if ((t & 31) == 0) rnorm[row] = s;
  }
  __syncthreads();
  f16x8_t o0, o1;
  #pragma unroll
  for (int r = 0; r < 8; r++) {
    int row = rg*8 + r;
    float scale = 11.313708498984761f / fmaxf(sqrtf(rnorm[row]), 1e-12f);
    float z0 = zlds[row][h0]*scale, z1 = zlds[row][h1]*scale;
    o0[r] = (half_t)z0;
    o1[r] = (half_t)z1;
    if (last) *reinterpret_cast<float2*>(&hout[(row0 + row)*HH + h0]) = make_float2(z0, z1);
  }
  half_t* hb = hT + (size_t)b*HH*LL + l0 + rg*8;
  *(f16x8_t*)&hb[(size_t)h0*LL] = o0;
  *(f16x8_t*)&hb[(size_t)h1*LL] = o1;
}

// ---------------- kE: out = h @ W_out + b_out ----------------
__global__ __launch_bounds__(256) void kE(const float* __restrict__ hin,
      const float4* __restrict__ wo4, const float* __restrict__ bout,
      float* __restrict__ out) {
  __shared__ float hs[64][HH];
  size_t row0 = (size_t)blockIdx.x * 64;
  int t = threadIdx.x;
  #pragma unroll
  for (int k = 0; k < 8; k++) {
    int idx = t + k*256;
    int r = idx >> 5, c4 = idx & 31;
    *reinterpret_cast<float4*>(&hs[r][c4*4]) =
        *reinterpret_cast<const float4*>(&hin[(row0 + r)*HH + c4*4]);
  }
  __syncthreads();
  int ct = t & 31, rg = t >> 5;
  float acc[8][2];
  float b0 = bout[2*ct], b1 = bout[2*ct+1];
  #pragma unroll
  for (int r = 0; r < 8; r++) { acc[r][0] = b0; acc[r][1] = b1; }
  for (int h4 = 0; h4 < 32; h4++) {
    float4 w0 = wo4[h4*64 + 2*ct];
    float4 w1 = wo4[h4*64 + 2*ct+1];
    #pragma unroll
    for (int r = 0; r < 8; r++) {
      const float4 h4v = *reinterpret_cast<const float4*>(&hs[rg*8 + r][h4*4]);
      acc[r][0] = fmaf(h4v.x, w0.x, fmaf(h4v.y, w0.y, fmaf(h4v.z, w0.z, fmaf(h4v.w, w0.w, acc[r][0]))));
      acc[r][1] = fmaf(h4v.x, w1.x, fmaf(h4v.y, w1.y, fmaf(h4v.z, w1.z, fmaf(h4v.w, w1.w, acc[r][1]))));
    }
  }
  #pragma unroll
  for (int r = 0; r < 8; r++) {
    float2 v = make_float2(acc[r][0], acc[r][1]);
    *reinterpret_cast<float2*>(&out[(row0 + rg*8 + r)*DD + 2*ct]) = v;
  }
}

extern "C" void kernel_launch(void* const* d_in, const int* in_sizes, int n_in,
                              void* d_out, int out_size, void* d_ws, size_t ws_size,
                              hipStream_t stream) {
  const float* x     = (const float*)d_in[0];
  const float* Win   = (const float*)d_in[1];
  const float* bin   = (const float*)d_in[2];
  const float* logdt = (const float*)d_in[3];
  const float* logA  = (const float*)d_in[4];
  const float* Aim   = (const float*)d_in[5];
  const float* Cre   = (const float*)d_in[6];
  const float* Cim   = (const float*)d_in[7];
  const float* Dsk   = (const float*)d_in[8];
  const float* Wglu  = (const float*)d_in[9];
  const float* bglu  = (const float*)d_in[10];
  const float* Wout  = (const float*)d_in[11];
  const float* bout  = (const float*)d_in[12];
  float* out = (float*)d_out;

  // SinitB eliminated by kG fusion; Amat3 un-aliased. Total ≈ 77.3 MB (well under
  // the proven-safe 104.2MB; round-10's 110.8MB overflowed).
  float* ws   = (float*)d_ws;
  float* wb3  = ws;                          // 3*16384
  float* wl3  = wb3 + 3*SZ_WB;               // 3*16384
  float* wgtF = wl3 + 3*SZ_WB;               // 49152
  float* wo4  = wgtF + SZ_WGT;               // 8192
  float* wi4  = wo4 + SZ_WO4;                // 8192
  float* amF  = wi4 + SZ_WI4;                // Amat3 f16: 3*786432 (9.4MB)
  float* htF  = amF + 3*SZ_AM;               // hT f16 (16.8MB)
  float* ytF  = htF + SZ_HT;                 // yT f16 (16.8MB)
  float* hA   = ytF + SZ_YT;                 // fp32 (33.6MB, last layer only)
  half_t* wgt    = (half_t*)wgtF;
  half_t* Amat3  = (half_t*)amF;
  half_t* hT     = (half_t*)htF;
  half_t* yT     = (half_t*)ytF;

  kW1<<<dim3(48), dim3(256), 0, stream>>>(Wglu, wgt);
  kW2<<<dim3(8),  dim3(256), 0, stream>>>(Wout, (float4*)wo4);
  kW3<<<dim3(8),  dim3(256), 0, stream>>>(Win,  (float4*)wi4);
  kP2<<<dim3(96), dim3(256), 0, stream>>>(logdt, logA, Aim, Cre, Cim, wb3, wl3, Amat3);
  kIn<<<dim3(2048), dim3(256), 0, stream>>>(x, (const float4*)wi4, bin, hT);

  for (int layer = 0; layer < NLAYER; ++layer) {
    const float* wb = wb3 + (size_t)layer*SZ_WB;
    const float* wl = wl3 + (size_t)layer*SZ_WB;
    const half_t* Amat = Amat3 + (size_t)layer*HH*64*192;
    kG<<<dim3(1024), dim3(256), 0, stream>>>(hT, wb, wl, Amat, yT);
    kD<<<dim3(2048), dim3(256), 0, stream>>>(yT, hT, Dsk + layer*HH,
                       wgt + (size_t)layer*256*HH,
                       bglu + layer*2*HH, hT, hA, (layer == NLAYER-1) ? 1 : 0);
  }
  kE<<<dim3(1024), dim3(256), 0, stream>>>(hA, (const float4*)wo4, bout, out);
}